// Round 1
// baseline (760.493 us; speedup 1.0000x reference)
//
#include <hip/hip_runtime.h>
#include <math.h>

#define N_NODES 50000
#define N_EDGES 800000
#define N_GRAPHS 64
#define NEG_SLOPE 0.2f

__device__ __forceinline__ float lrelu(float x) { return x > 0.f ? x : NEG_SLOPE * x; }

__device__ __forceinline__ int lower_bound_i(const int* __restrict__ a, int n, int v) {
    int lo = 0, hi = n;
    while (lo < hi) { int m = (lo + hi) >> 1; if (a[m] < v) lo = m + 1; else hi = m; }
    return lo;
}

// ---------------- CSR build ----------------
__global__ void k_zero(int* __restrict__ p, int n) {
    int i = blockIdx.x * blockDim.x + threadIdx.x;
    if (i < n) p[i] = 0;
}

__global__ void k_count(const int* __restrict__ dst, int* __restrict__ cnt) {
    int e = blockIdx.x * blockDim.x + threadIdx.x;
    if (e < N_EDGES) atomicAdd(&cnt[dst[e]], 1);
}

__global__ __launch_bounds__(256) void k_scan(const int* __restrict__ cnt,
                                              int* __restrict__ row_start,
                                              int* __restrict__ cursor) {
    __shared__ int tsum[256];
    __shared__ int total_s;
    const int t = threadIdx.x;
    const int chunk = (N_NODES + 255) / 256;
    int beg = t * chunk, end = min(N_NODES, beg + chunk);
    int s = 0;
    for (int i = beg; i < end; ++i) s += cnt[i];
    tsum[t] = s;
    __syncthreads();
    if (t == 0) {
        int run = 0;
        for (int j = 0; j < 256; ++j) { int v = tsum[j]; tsum[j] = run; run += v; }
        total_s = run;
    }
    __syncthreads();
    int run = tsum[t];
    for (int i = beg; i < end; ++i) {
        row_start[i] = run;
        cursor[i] = run;
        run += cnt[i];
    }
    if (t == 0) row_start[N_NODES] = total_s;
}

__global__ void k_fill(const int* __restrict__ src, const int* __restrict__ dst,
                       int* __restrict__ cursor, int* __restrict__ csr_src) {
    int e = blockIdx.x * blockDim.x + threadIdx.x;
    if (e < N_EDGES) {
        int d = dst[e];
        int p = atomicAdd(&cursor[d], 1);
        csr_src[p] = src[e];
    }
}

// ---------------- Layer 1: x@W1 (K=5) + attention logits ----------------
__global__ __launch_bounds__(256) void k_gemm1(const float* __restrict__ x,
                                               const float* __restrict__ W1,
                                               const float* __restrict__ att_s,
                                               const float* __restrict__ att_d,
                                               float* __restrict__ h1,
                                               float* __restrict__ a_s,
                                               float* __restrict__ a_d) {
    __shared__ float Ws[5 * 256];
    const int t = threadIdx.x;
    for (int i = t; i < 5 * 256; i += 256) Ws[i] = W1[i];
    __syncthreads();
    const int head = t >> 6, lane = t & 63;
    const float asw = att_s[t];   // att_src1[head][lane]
    const float adw = att_d[t];
    const int node0 = blockIdx.x * 8;
    for (int i = 0; i < 8; ++i) {
        int n = node0 + i;
        if (n >= N_NODES) break;
        float x0 = x[n * 5 + 0], x1 = x[n * 5 + 1], x2 = x[n * 5 + 2],
              x3 = x[n * 5 + 3], x4 = x[n * 5 + 4];
        float h = x0 * Ws[t] + x1 * Ws[256 + t] + x2 * Ws[512 + t] +
                  x3 * Ws[768 + t] + x4 * Ws[1024 + t];
        h1[(size_t)n * 256 + t] = h;
        float vs = h * asw, vd = h * adw;
        for (int off = 32; off; off >>= 1) {
            vs += __shfl_xor(vs, off, 64);
            vd += __shfl_xor(vd, off, 64);
        }
        if (lane == 0) { a_s[n * 4 + head] = vs; a_d[n * 4 + head] = vd; }
    }
}

// ---------------- Layer 1 aggregation: wave per dst node ----------------
__global__ __launch_bounds__(256) void k_agg1(const float* __restrict__ h1,
                                              const float4* __restrict__ asv,
                                              const float4* __restrict__ adv,
                                              const int* __restrict__ row_start,
                                              const int* __restrict__ csr_src,
                                              const float* __restrict__ b1,
                                              float* __restrict__ out1) {
    const int wave = threadIdx.x >> 6, lane = threadIdx.x & 63;
    const int d = blockIdx.x * 4 + wave;
    if (d >= N_NODES) return;
    const int beg = row_start[d], end = row_start[d + 1];
    const float4 ad = adv[d];

    // pass 1: segment max (self loop + edges)
    float4 as = asv[d];
    float m0 = lrelu(as.x + ad.x), m1 = lrelu(as.y + ad.y);
    float m2 = lrelu(as.z + ad.z), m3 = lrelu(as.w + ad.w);
    for (int j = beg; j < end; ++j) {
        int s = csr_src[j];
        float4 a = asv[s];
        m0 = fmaxf(m0, lrelu(a.x + ad.x));
        m1 = fmaxf(m1, lrelu(a.y + ad.y));
        m2 = fmaxf(m2, lrelu(a.z + ad.z));
        m3 = fmaxf(m3, lrelu(a.w + ad.w));
    }
    // pass 2: denom + weighted sum
    float den0 = 0, den1 = 0, den2 = 0, den3 = 0;
    float acc0 = 0, acc1 = 0, acc2 = 0, acc3 = 0;
    {   // self loop
        float w0 = expf(lrelu(as.x + ad.x) - m0);
        float w1 = expf(lrelu(as.y + ad.y) - m1);
        float w2 = expf(lrelu(as.z + ad.z) - m2);
        float w3 = expf(lrelu(as.w + ad.w) - m3);
        den0 += w0; den1 += w1; den2 += w2; den3 += w3;
        const float* hp = h1 + (size_t)d * 256;
        acc0 += w0 * hp[lane];
        acc1 += w1 * hp[64 + lane];
        acc2 += w2 * hp[128 + lane];
        acc3 += w3 * hp[192 + lane];
    }
    for (int j = beg; j < end; ++j) {
        int s = csr_src[j];
        float4 a = asv[s];
        float w0 = expf(lrelu(a.x + ad.x) - m0);
        float w1 = expf(lrelu(a.y + ad.y) - m1);
        float w2 = expf(lrelu(a.z + ad.z) - m2);
        float w3 = expf(lrelu(a.w + ad.w) - m3);
        den0 += w0; den1 += w1; den2 += w2; den3 += w3;
        const float* hp = h1 + (size_t)s * 256;
        acc0 += w0 * hp[lane];
        acc1 += w1 * hp[64 + lane];
        acc2 += w2 * hp[128 + lane];
        acc3 += w3 * hp[192 + lane];
    }
    float* op = out1 + (size_t)d * 256;
    op[lane]       = fmaxf(acc0 / (den0 + 1e-16f) + b1[lane], 0.f);
    op[64 + lane]  = fmaxf(acc1 / (den1 + 1e-16f) + b1[64 + lane], 0.f);
    op[128 + lane] = fmaxf(acc2 / (den2 + 1e-16f) + b1[128 + lane], 0.f);
    op[192 + lane] = fmaxf(acc3 / (den3 + 1e-16f) + b1[192 + lane], 0.f);
}

// ---------------- Layer 2: out1@W2 (256->64) + attention logits ----------------
__global__ __launch_bounds__(256) void k_gemm2(const float* __restrict__ in,
                                               const float* __restrict__ W2,
                                               const float* __restrict__ att_s2,
                                               const float* __restrict__ att_d2,
                                               float* __restrict__ h2,
                                               float* __restrict__ a_s2,
                                               float* __restrict__ a_d2) {
    __shared__ float Ws[256 * 64];  // 64 KB
    const int t = threadIdx.x;
    for (int i = t; i < 256 * 64; i += 256) Ws[i] = W2[i];
    __syncthreads();
    const int wave = t >> 6, lane = t & 63;
    const float asw = att_s2[lane], adw = att_d2[lane];
    const int n0 = blockIdx.x * 32 + wave * 8;
    for (int i = 0; i < 8; ++i) {
        int n = n0 + i;
        if (n >= N_NODES) break;
        const float4* xv = (const float4*)(in + (size_t)n * 256);
        float acc = 0.f;
        for (int k = 0; k < 64; ++k) {
            float4 v = xv[k];
            const float* wrow = Ws + 4 * k * 64;
            acc += v.x * wrow[lane] + v.y * wrow[64 + lane] +
                   v.z * wrow[128 + lane] + v.w * wrow[192 + lane];
        }
        h2[(size_t)n * 64 + lane] = acc;
        float vs = acc * asw, vd = acc * adw;
        for (int off = 32; off; off >>= 1) {
            vs += __shfl_xor(vs, off, 64);
            vd += __shfl_xor(vd, off, 64);
        }
        if (lane == 0) { a_s2[n] = vs; a_d2[n] = vd; }
    }
}

// ---------------- Layer 2 aggregation: wave per dst node ----------------
__global__ __launch_bounds__(256) void k_agg2(const float* __restrict__ h2,
                                              const float* __restrict__ as_,
                                              const float* __restrict__ ad_,
                                              const int* __restrict__ row_start,
                                              const int* __restrict__ csr_src,
                                              const float* __restrict__ b2,
                                              float* __restrict__ out2) {
    const int wave = threadIdx.x >> 6, lane = threadIdx.x & 63;
    const int d = blockIdx.x * 4 + wave;
    if (d >= N_NODES) return;
    const int beg = row_start[d], end = row_start[d + 1];
    const float adl = ad_[d];
    float asl = as_[d];
    float m = lrelu(asl + adl);
    for (int j = beg; j < end; ++j) {
        m = fmaxf(m, lrelu(as_[csr_src[j]] + adl));
    }
    float den = 0.f, acc = 0.f;
    {
        float w = expf(lrelu(asl + adl) - m);
        den += w;
        acc += w * h2[(size_t)d * 64 + lane];
    }
    for (int j = beg; j < end; ++j) {
        int s = csr_src[j];
        float w = expf(lrelu(as_[s] + adl) - m);
        den += w;
        acc += w * h2[(size_t)s * 64 + lane];
    }
    out2[(size_t)d * 64 + lane] = fmaxf(acc / (den + 1e-16f) + b2[lane], 0.f);
}

// ---------------- Global mean pool + linear ----------------
__global__ __launch_bounds__(256) void k_pool(const float* __restrict__ out2,
                                              const int* __restrict__ batch,
                                              const float* __restrict__ linW,
                                              const float* __restrict__ linb,
                                              float* __restrict__ out) {
    const int g = blockIdx.x;
    const int t = threadIdx.x, wave = t >> 6, lane = t & 63;
    __shared__ int s_beg, s_end;
    __shared__ float red[4][64];
    if (t == 0) {
        s_beg = lower_bound_i(batch, N_NODES, g);
        s_end = lower_bound_i(batch, N_NODES, g + 1);
    }
    __syncthreads();
    const int beg = s_beg, end = s_end;
    float sum = 0.f;
    for (int n = beg + wave; n < end; n += 4) sum += out2[(size_t)n * 64 + lane];
    red[wave][lane] = sum;
    __syncthreads();
    if (wave == 0) {
        float s = red[0][lane] + red[1][lane] + red[2][lane] + red[3][lane];
        float cnt = (float)(end - beg);
        red[0][lane] = s / fmaxf(cnt, 1.0f);
    }
    __syncthreads();
    if (t < 2) {
        float acc = linb[t];
        for (int c = 0; c < 64; ++c) acc += red[0][c] * linW[c * 2 + t];
        out[g * 2 + t] = acc;
    }
}

extern "C" void kernel_launch(void* const* d_in, const int* in_sizes, int n_in,
                              void* d_out, int out_size, void* d_ws, size_t ws_size,
                              hipStream_t stream) {
    const float* x    = (const float*)d_in[0];
    const int*   ei   = (const int*)d_in[1];
    const int*   bat  = (const int*)d_in[2];
    const float* W1   = (const float*)d_in[3];
    const float* as1  = (const float*)d_in[4];
    const float* ad1  = (const float*)d_in[5];
    const float* b1   = (const float*)d_in[6];
    const float* W2   = (const float*)d_in[7];
    const float* as2  = (const float*)d_in[8];
    const float* ad2  = (const float*)d_in[9];
    const float* b2   = (const float*)d_in[10];
    const float* linW = (const float*)d_in[11];
    const float* linb = (const float*)d_in[12];
    float* out = (float*)d_out;

    const int* src = ei;
    const int* dst = ei + N_EDGES;

    char* w = (char*)d_ws;
    float* h1   = (float*)w; w += (size_t)N_NODES * 256 * 4;
    float* out1 = (float*)w; w += (size_t)N_NODES * 256 * 4;
    float* a_s1 = (float*)w; w += (size_t)N_NODES * 4 * 4;
    float* a_d1 = (float*)w; w += (size_t)N_NODES * 4 * 4;
    float* h2   = (float*)w; w += (size_t)N_NODES * 64 * 4;
    float* out2 = (float*)w; w += (size_t)N_NODES * 64 * 4;
    float* a_s2 = (float*)w; w += (size_t)N_NODES * 4;
    float* a_d2 = (float*)w; w += (size_t)N_NODES * 4;
    int* counts    = (int*)w; w += (size_t)N_NODES * 4;
    int* row_start = (int*)w; w += (size_t)(N_NODES + 64) * 4;
    int* cursor    = (int*)w; w += (size_t)N_NODES * 4;
    int* csr_src   = (int*)w; w += (size_t)N_EDGES * 4;

    // CSR build
    k_zero<<<(N_NODES + 255) / 256, 256, 0, stream>>>(counts, N_NODES);
    k_count<<<(N_EDGES + 255) / 256, 256, 0, stream>>>(dst, counts);
    k_scan<<<1, 256, 0, stream>>>(counts, row_start, cursor);
    k_fill<<<(N_EDGES + 255) / 256, 256, 0, stream>>>(src, dst, cursor, csr_src);

    // Layer 1
    k_gemm1<<<(N_NODES + 7) / 8, 256, 0, stream>>>(x, W1, as1, ad1, h1, a_s1, a_d1);
    k_agg1<<<(N_NODES + 3) / 4, 256, 0, stream>>>(h1, (const float4*)a_s1, (const float4*)a_d1,
                                                  row_start, csr_src, b1, out1);
    // Layer 2
    k_gemm2<<<(N_NODES + 31) / 32, 256, 0, stream>>>(out1, W2, as2, ad2, h2, a_s2, a_d2);
    k_agg2<<<(N_NODES + 3) / 4, 256, 0, stream>>>(h2, a_s2, a_d2, row_start, csr_src, b2, out2);

    // Pool + linear
    k_pool<<<N_GRAPHS, 256, 0, stream>>>(out2, bat, linW, linb, out);
}

// Round 2
// 627.167 us; speedup vs baseline: 1.2126x; 1.2126x over previous
//
#include <hip/hip_runtime.h>
#include <math.h>

#define N_NODES 50000
#define N_EDGES 800000
#define N_GRAPHS 64
#define NEG_SLOPE 0.2f

__device__ __forceinline__ float lrelu(float x) { return x > 0.f ? x : NEG_SLOPE * x; }

__device__ __forceinline__ int lower_bound_i(const int* __restrict__ a, int n, int v) {
    int lo = 0, hi = n;
    while (lo < hi) { int m = (lo + hi) >> 1; if (a[m] < v) lo = m + 1; else hi = m; }
    return lo;
}

// ---------------- CSR build ----------------
__global__ void k_zero(int* __restrict__ p, int n) {
    int i = blockIdx.x * blockDim.x + threadIdx.x;
    if (i < n) p[i] = 0;
}

__global__ void k_count(const int* __restrict__ dst, int* __restrict__ cnt) {
    int e = blockIdx.x * blockDim.x + threadIdx.x;
    if (e < N_EDGES) atomicAdd(&cnt[dst[e]], 1);
}

__global__ __launch_bounds__(256) void k_scan(const int* __restrict__ cnt,
                                              int* __restrict__ row_start,
                                              int* __restrict__ cursor) {
    __shared__ int tsum[256];
    __shared__ int total_s;
    const int t = threadIdx.x;
    const int chunk = (N_NODES + 255) / 256;
    int beg = t * chunk, end = min(N_NODES, beg + chunk);
    int s = 0;
    for (int i = beg; i < end; ++i) s += cnt[i];
    tsum[t] = s;
    __syncthreads();
    if (t == 0) {
        int run = 0;
        for (int j = 0; j < 256; ++j) { int v = tsum[j]; tsum[j] = run; run += v; }
        total_s = run;
    }
    __syncthreads();
    int run = tsum[t];
    for (int i = beg; i < end; ++i) {
        row_start[i] = run;
        cursor[i] = run;
        run += cnt[i];
    }
    if (t == 0) row_start[N_NODES] = total_s;
}

__global__ void k_fill(const int* __restrict__ src, const int* __restrict__ dst,
                       int* __restrict__ cursor, int* __restrict__ csr_src) {
    int e = blockIdx.x * blockDim.x + threadIdx.x;
    if (e < N_EDGES) {
        int d = dst[e];
        int p = atomicAdd(&cursor[d], 1);
        csr_src[p] = src[e];
    }
}

// ---------------- Layer 1: x@W1 (K=5) + attention logits ----------------
// h1 stored PERMUTED: h1v[n*64 + ch] = float4(heads 0..3 at channel ch)
__global__ __launch_bounds__(256) void k_gemm1(const float* __restrict__ x,
                                               const float* __restrict__ W1,
                                               const float* __restrict__ att_s,
                                               const float* __restrict__ att_d,
                                               float4* __restrict__ h1v,
                                               float4* __restrict__ a_s,
                                               float4* __restrict__ a_d) {
    __shared__ float Ws[5 * 256];
    const int t = threadIdx.x;
    for (int i = t; i < 5 * 256; i += 256) Ws[i] = W1[i];
    __syncthreads();
    const int wave = t >> 6, lane = t & 63;
    const int n = blockIdx.x * 4 + wave;
    if (n >= N_NODES) return;
    float x0 = x[n * 5 + 0], x1 = x[n * 5 + 1], x2 = x[n * 5 + 2],
          x3 = x[n * 5 + 3], x4 = x[n * 5 + 4];
    float h[4], vs[4], vd[4];
#pragma unroll
    for (int hd = 0; hd < 4; ++hd) {
        const int c = hd * 64 + lane;
        h[hd] = x0 * Ws[c] + x1 * Ws[256 + c] + x2 * Ws[512 + c] +
                x3 * Ws[768 + c] + x4 * Ws[1024 + c];
        vs[hd] = h[hd] * att_s[c];
        vd[hd] = h[hd] * att_d[c];
    }
#pragma unroll
    for (int off = 32; off; off >>= 1) {
#pragma unroll
        for (int hd = 0; hd < 4; ++hd) {
            vs[hd] += __shfl_xor(vs[hd], off, 64);
            vd[hd] += __shfl_xor(vd[hd], off, 64);
        }
    }
    h1v[(size_t)n * 64 + lane] = make_float4(h[0], h[1], h[2], h[3]);
    if (lane == 0) {
        a_s[n] = make_float4(vs[0], vs[1], vs[2], vs[3]);
        a_d[n] = make_float4(vd[0], vd[1], vd[2], vd[3]);
    }
}

// ---------------- Layer 1 aggregation: wave per dst node ----------------
__global__ __launch_bounds__(256) void k_agg1(const float4* __restrict__ h1v,
                                              const float4* __restrict__ asv,
                                              const float4* __restrict__ adv,
                                              const int* __restrict__ row_start,
                                              const int* __restrict__ csr_src,
                                              const float* __restrict__ b1,
                                              float4* __restrict__ out1v) {
    const int wave = threadIdx.x >> 6, lane = threadIdx.x & 63;
    const int d = blockIdx.x * 4 + wave;
    if (d >= N_NODES) return;
    const int beg = row_start[d], end = row_start[d + 1];
    const float4 ad = adv[d];
    const float4 as = asv[d];

    float e0 = lrelu(as.x + ad.x), e1 = lrelu(as.y + ad.y);
    float e2 = lrelu(as.z + ad.z), e3 = lrelu(as.w + ad.w);

    // pass 1: segment max, lane-parallel over edges
    float m0 = e0, m1 = e1, m2 = e2, m3 = e3;
    for (int j = beg + lane; j < end; j += 64) {
        int s = csr_src[j];
        float4 a = asv[s];
        m0 = fmaxf(m0, lrelu(a.x + ad.x));
        m1 = fmaxf(m1, lrelu(a.y + ad.y));
        m2 = fmaxf(m2, lrelu(a.z + ad.z));
        m3 = fmaxf(m3, lrelu(a.w + ad.w));
    }
#pragma unroll
    for (int off = 32; off; off >>= 1) {
        m0 = fmaxf(m0, __shfl_xor(m0, off, 64));
        m1 = fmaxf(m1, __shfl_xor(m1, off, 64));
        m2 = fmaxf(m2, __shfl_xor(m2, off, 64));
        m3 = fmaxf(m3, __shfl_xor(m3, off, 64));
    }

    // pass 2: weights lane-parallel, gather channel-parallel
    float den0, den1, den2, den3;
    float acc0, acc1, acc2, acc3;
    {
        float w0 = expf(e0 - m0), w1 = expf(e1 - m1);
        float w2 = expf(e2 - m2), w3 = expf(e3 - m3);
        den0 = (lane == 0) ? w0 : 0.f;
        den1 = (lane == 0) ? w1 : 0.f;
        den2 = (lane == 0) ? w2 : 0.f;
        den3 = (lane == 0) ? w3 : 0.f;
        float4 hv = h1v[(size_t)d * 64 + lane];
        acc0 = w0 * hv.x; acc1 = w1 * hv.y; acc2 = w2 * hv.z; acc3 = w3 * hv.w;
    }
    for (int c = beg; c < end; c += 64) {
        int rem = end - c; if (rem > 64) rem = 64;
        int sreg = 0;
        float w0r = 0.f, w1r = 0.f, w2r = 0.f, w3r = 0.f;
        if (lane < rem) {
            sreg = csr_src[c + lane];
            float4 a = asv[sreg];
            w0r = expf(lrelu(a.x + ad.x) - m0);
            w1r = expf(lrelu(a.y + ad.y) - m1);
            w2r = expf(lrelu(a.z + ad.z) - m2);
            w3r = expf(lrelu(a.w + ad.w) - m3);
            den0 += w0r; den1 += w1r; den2 += w2r; den3 += w3r;
        }
        for (int e = 0; e < rem; ++e) {
            int s = __shfl(sreg, e, 64);
            float w0 = __shfl(w0r, e, 64), w1 = __shfl(w1r, e, 64);
            float w2 = __shfl(w2r, e, 64), w3 = __shfl(w3r, e, 64);
            float4 hv = h1v[(size_t)s * 64 + lane];
            acc0 += w0 * hv.x; acc1 += w1 * hv.y;
            acc2 += w2 * hv.z; acc3 += w3 * hv.w;
        }
    }
#pragma unroll
    for (int off = 32; off; off >>= 1) {
        den0 += __shfl_xor(den0, off, 64);
        den1 += __shfl_xor(den1, off, 64);
        den2 += __shfl_xor(den2, off, 64);
        den3 += __shfl_xor(den3, off, 64);
    }
    float o0 = fmaxf(acc0 / (den0 + 1e-16f) + b1[lane], 0.f);
    float o1 = fmaxf(acc1 / (den1 + 1e-16f) + b1[64 + lane], 0.f);
    float o2 = fmaxf(acc2 / (den2 + 1e-16f) + b1[128 + lane], 0.f);
    float o3 = fmaxf(acc3 / (den3 + 1e-16f) + b1[192 + lane], 0.f);
    out1v[(size_t)d * 64 + lane] = make_float4(o0, o1, o2, o3);
}

// ---------------- Layer 2: out1@W2 (256->64) + attention logits ----------------
// input is PERMUTED: in[n*64+k] = float4 with channels c = {k, 64+k, 128+k, 192+k}
__global__ __launch_bounds__(256) void k_gemm2(const float4* __restrict__ in,
                                               const float* __restrict__ W2,
                                               const float* __restrict__ att_s2,
                                               const float* __restrict__ att_d2,
                                               float* __restrict__ h2,
                                               float* __restrict__ a_s2,
                                               float* __restrict__ a_d2) {
    __shared__ float Ws[256 * 64];  // 64 KB
    const int t = threadIdx.x;
    for (int i = t; i < 256 * 64; i += 256) Ws[i] = W2[i];
    __syncthreads();
    const int wave = t >> 6, lane = t & 63;
    const float asw = att_s2[lane], adw = att_d2[lane];
    const int n0 = blockIdx.x * 32 + wave * 8;
    for (int i = 0; i < 8; ++i) {
        int n = n0 + i;
        if (n >= N_NODES) break;
        const float4* xv = in + (size_t)n * 64;
        float acc = 0.f;
        for (int k = 0; k < 64; ++k) {
            float4 v = xv[k];
            acc += v.x * Ws[k * 64 + lane] + v.y * Ws[(64 + k) * 64 + lane] +
                   v.z * Ws[(128 + k) * 64 + lane] + v.w * Ws[(192 + k) * 64 + lane];
        }
        h2[(size_t)n * 64 + lane] = acc;
        float vs = acc * asw, vd = acc * adw;
#pragma unroll
        for (int off = 32; off; off >>= 1) {
            vs += __shfl_xor(vs, off, 64);
            vd += __shfl_xor(vd, off, 64);
        }
        if (lane == 0) { a_s2[n] = vs; a_d2[n] = vd; }
    }
}

// ---------------- Layer 2 aggregation: wave per dst node ----------------
__global__ __launch_bounds__(256) void k_agg2(const float* __restrict__ h2,
                                              const float* __restrict__ as_,
                                              const float* __restrict__ ad_,
                                              const int* __restrict__ row_start,
                                              const int* __restrict__ csr_src,
                                              const float* __restrict__ b2,
                                              float* __restrict__ out2) {
    const int wave = threadIdx.x >> 6, lane = threadIdx.x & 63;
    const int d = blockIdx.x * 4 + wave;
    if (d >= N_NODES) return;
    const int beg = row_start[d], end = row_start[d + 1];
    const float adl = ad_[d];
    const float eself = lrelu(as_[d] + adl);

    float m = eself;
    for (int j = beg + lane; j < end; j += 64) {
        m = fmaxf(m, lrelu(as_[csr_src[j]] + adl));
    }
#pragma unroll
    for (int off = 32; off; off >>= 1) m = fmaxf(m, __shfl_xor(m, off, 64));

    float den, acc;
    {
        float w = expf(eself - m);
        den = (lane == 0) ? w : 0.f;
        acc = w * h2[(size_t)d * 64 + lane];
    }
    for (int c = beg; c < end; c += 64) {
        int rem = end - c; if (rem > 64) rem = 64;
        int sreg = 0;
        float wr = 0.f;
        if (lane < rem) {
            sreg = csr_src[c + lane];
            wr = expf(lrelu(as_[sreg] + adl) - m);
            den += wr;
        }
        for (int e = 0; e < rem; ++e) {
            int s = __shfl(sreg, e, 64);
            float w = __shfl(wr, e, 64);
            acc += w * h2[(size_t)s * 64 + lane];
        }
    }
#pragma unroll
    for (int off = 32; off; off >>= 1) den += __shfl_xor(den, off, 64);
    out2[(size_t)d * 64 + lane] = fmaxf(acc / (den + 1e-16f) + b2[lane], 0.f);
}

// ---------------- Global mean pool + linear ----------------
__global__ __launch_bounds__(256) void k_pool(const float* __restrict__ out2,
                                              const int* __restrict__ batch,
                                              const float* __restrict__ linW,
                                              const float* __restrict__ linb,
                                              float* __restrict__ out) {
    const int g = blockIdx.x;
    const int t = threadIdx.x, wave = t >> 6, lane = t & 63;
    __shared__ int s_beg, s_end;
    __shared__ float red[4][64];
    if (t == 0) {
        s_beg = lower_bound_i(batch, N_NODES, g);
        s_end = lower_bound_i(batch, N_NODES, g + 1);
    }
    __syncthreads();
    const int beg = s_beg, end = s_end;
    float sum = 0.f;
    for (int n = beg + wave; n < end; n += 4) sum += out2[(size_t)n * 64 + lane];
    red[wave][lane] = sum;
    __syncthreads();
    if (wave == 0) {
        float s = red[0][lane] + red[1][lane] + red[2][lane] + red[3][lane];
        float cnt = (float)(end - beg);
        red[0][lane] = s / fmaxf(cnt, 1.0f);
    }
    __syncthreads();
    if (t < 2) {
        float acc = linb[t];
        for (int c = 0; c < 64; ++c) acc += red[0][c] * linW[c * 2 + t];
        out[g * 2 + t] = acc;
    }
}

extern "C" void kernel_launch(void* const* d_in, const int* in_sizes, int n_in,
                              void* d_out, int out_size, void* d_ws, size_t ws_size,
                              hipStream_t stream) {
    const float* x    = (const float*)d_in[0];
    const int*   ei   = (const int*)d_in[1];
    const int*   bat  = (const int*)d_in[2];
    const float* W1   = (const float*)d_in[3];
    const float* as1  = (const float*)d_in[4];
    const float* ad1  = (const float*)d_in[5];
    const float* b1   = (const float*)d_in[6];
    const float* W2   = (const float*)d_in[7];
    const float* as2  = (const float*)d_in[8];
    const float* ad2  = (const float*)d_in[9];
    const float* b2   = (const float*)d_in[10];
    const float* linW = (const float*)d_in[11];
    const float* linb = (const float*)d_in[12];
    float* out = (float*)d_out;

    const int* src = ei;
    const int* dst = ei + N_EDGES;

    char* w = (char*)d_ws;
    float4* h1v  = (float4*)w; w += (size_t)N_NODES * 64 * 16;
    float4* out1 = (float4*)w; w += (size_t)N_NODES * 64 * 16;
    float4* a_s1 = (float4*)w; w += (size_t)N_NODES * 16;
    float4* a_d1 = (float4*)w; w += (size_t)N_NODES * 16;
    float* h2    = (float*)w; w += (size_t)N_NODES * 64 * 4;
    float* out2  = (float*)w; w += (size_t)N_NODES * 64 * 4;
    float* a_s2  = (float*)w; w += (size_t)N_NODES * 4;
    float* a_d2  = (float*)w; w += (size_t)N_NODES * 4;
    int* counts    = (int*)w; w += (size_t)N_NODES * 4;
    int* row_start = (int*)w; w += (size_t)(N_NODES + 64) * 4;
    int* cursor    = (int*)w; w += (size_t)N_NODES * 4;
    int* csr_src   = (int*)w; w += (size_t)N_EDGES * 4;

    // CSR build
    k_zero<<<(N_NODES + 255) / 256, 256, 0, stream>>>(counts, N_NODES);
    k_count<<<(N_EDGES + 255) / 256, 256, 0, stream>>>(dst, counts);
    k_scan<<<1, 256, 0, stream>>>(counts, row_start, cursor);
    k_fill<<<(N_EDGES + 255) / 256, 256, 0, stream>>>(src, dst, cursor, csr_src);

    // Layer 1
    k_gemm1<<<(N_NODES + 3) / 4, 256, 0, stream>>>(x, W1, as1, ad1, h1v, a_s1, a_d1);
    k_agg1<<<(N_NODES + 3) / 4, 256, 0, stream>>>(h1v, a_s1, a_d1, row_start, csr_src, b1, out1);
    // Layer 2
    k_gemm2<<<(N_NODES + 31) / 32, 256, 0, stream>>>(out1, W2, as2, ad2, h2, a_s2, a_d2);
    k_agg2<<<(N_NODES + 3) / 4, 256, 0, stream>>>(h2, a_s2, a_d2, row_start, csr_src, b2, out2);

    // Pool + linear
    k_pool<<<N_GRAPHS, 256, 0, stream>>>(out2, bat, linW, linb, out);
}

// Round 3
// 600.280 us; speedup vs baseline: 1.2669x; 1.0448x over previous
//
#include <hip/hip_runtime.h>
#include <math.h>

#define N_NODES 50000
#define N_EDGES 800000
#define N_GRAPHS 64
#define NEG_SLOPE 0.2f

__device__ __forceinline__ float lrelu(float x) { return x > 0.f ? x : NEG_SLOPE * x; }

__device__ __forceinline__ int lower_bound_i(const int* __restrict__ a, int n, int v) {
    int lo = 0, hi = n;
    while (lo < hi) { int m = (lo + hi) >> 1; if (a[m] < v) lo = m + 1; else hi = m; }
    return lo;
}

// ---------------- CSR build ----------------
__global__ void k_zero(int* __restrict__ p, int n) {
    int i = blockIdx.x * blockDim.x + threadIdx.x;
    if (i < n) p[i] = 0;
}

__global__ void k_count(const int* __restrict__ dst, int* __restrict__ cnt) {
    int e = blockIdx.x * blockDim.x + threadIdx.x;
    if (e < N_EDGES) atomicAdd(&cnt[dst[e]], 1);
}

__global__ __launch_bounds__(256) void k_scan(const int* __restrict__ cnt,
                                              int* __restrict__ row_start,
                                              int* __restrict__ cursor) {
    __shared__ int tsum[256];
    __shared__ int total_s;
    const int t = threadIdx.x;
    const int chunk = (N_NODES + 255) / 256;
    int beg = t * chunk, end = min(N_NODES, beg + chunk);
    int s = 0;
    for (int i = beg; i < end; ++i) s += cnt[i];
    tsum[t] = s;
    __syncthreads();
    if (t == 0) {
        int run = 0;
        for (int j = 0; j < 256; ++j) { int v = tsum[j]; tsum[j] = run; run += v; }
        total_s = run;
    }
    __syncthreads();
    int run = tsum[t];
    for (int i = beg; i < end; ++i) {
        row_start[i] = run;
        cursor[i] = run;
        run += cnt[i];
    }
    if (t == 0) row_start[N_NODES] = total_s;
}

__global__ void k_fill(const int* __restrict__ src, const int* __restrict__ dst,
                       int* __restrict__ cursor, int* __restrict__ csr_src) {
    int e = blockIdx.x * blockDim.x + threadIdx.x;
    if (e < N_EDGES) {
        int d = dst[e];
        int p = atomicAdd(&cursor[d], 1);
        csr_src[p] = src[e];
    }
}

// ---------------- Layer 1: x@W1 (K=5) + attention logits ----------------
// h1 stored PERMUTED: h1v[n*64 + ch] = float4(heads 0..3 at channel ch)
__global__ __launch_bounds__(256) void k_gemm1(const float* __restrict__ x,
                                               const float* __restrict__ W1,
                                               const float* __restrict__ att_s,
                                               const float* __restrict__ att_d,
                                               float4* __restrict__ h1v,
                                               float4* __restrict__ a_s,
                                               float4* __restrict__ a_d) {
    __shared__ float Ws[5 * 256];
    const int t = threadIdx.x;
    for (int i = t; i < 5 * 256; i += 256) Ws[i] = W1[i];
    __syncthreads();
    const int wave = t >> 6, lane = t & 63;
    const int n = blockIdx.x * 4 + wave;
    if (n >= N_NODES) return;
    float x0 = x[n * 5 + 0], x1 = x[n * 5 + 1], x2 = x[n * 5 + 2],
          x3 = x[n * 5 + 3], x4 = x[n * 5 + 4];
    float h[4], vs[4], vd[4];
#pragma unroll
    for (int hd = 0; hd < 4; ++hd) {
        const int c = hd * 64 + lane;
        h[hd] = x0 * Ws[c] + x1 * Ws[256 + c] + x2 * Ws[512 + c] +
                x3 * Ws[768 + c] + x4 * Ws[1024 + c];
        vs[hd] = h[hd] * att_s[c];
        vd[hd] = h[hd] * att_d[c];
    }
#pragma unroll
    for (int off = 32; off; off >>= 1) {
#pragma unroll
        for (int hd = 0; hd < 4; ++hd) {
            vs[hd] += __shfl_xor(vs[hd], off, 64);
            vd[hd] += __shfl_xor(vd[hd], off, 64);
        }
    }
    h1v[(size_t)n * 64 + lane] = make_float4(h[0], h[1], h[2], h[3]);
    if (lane == 0) {
        a_s[n] = make_float4(vs[0], vs[1], vs[2], vs[3]);
        a_d[n] = make_float4(vd[0], vd[1], vd[2], vd[3]);
    }
}

// ---------------- Layer 1 aggregation: wave per dst node ----------------
__global__ __launch_bounds__(256) void k_agg1(const float4* __restrict__ h1v,
                                              const float4* __restrict__ asv,
                                              const float4* __restrict__ adv,
                                              const int* __restrict__ row_start,
                                              const int* __restrict__ csr_src,
                                              const float* __restrict__ b1,
                                              float4* __restrict__ out1v) {
    const int wave = threadIdx.x >> 6, lane = threadIdx.x & 63;
    const int d = blockIdx.x * 4 + wave;
    if (d >= N_NODES) return;
    const int beg = row_start[d], end = row_start[d + 1];
    const float4 ad = adv[d];
    const float4 as = asv[d];

    float e0 = lrelu(as.x + ad.x), e1 = lrelu(as.y + ad.y);
    float e2 = lrelu(as.z + ad.z), e3 = lrelu(as.w + ad.w);

    // pass 1: segment max, lane-parallel over edges
    float m0 = e0, m1 = e1, m2 = e2, m3 = e3;
    for (int j = beg + lane; j < end; j += 64) {
        int s = csr_src[j];
        float4 a = asv[s];
        m0 = fmaxf(m0, lrelu(a.x + ad.x));
        m1 = fmaxf(m1, lrelu(a.y + ad.y));
        m2 = fmaxf(m2, lrelu(a.z + ad.z));
        m3 = fmaxf(m3, lrelu(a.w + ad.w));
    }
#pragma unroll
    for (int off = 32; off; off >>= 1) {
        m0 = fmaxf(m0, __shfl_xor(m0, off, 64));
        m1 = fmaxf(m1, __shfl_xor(m1, off, 64));
        m2 = fmaxf(m2, __shfl_xor(m2, off, 64));
        m3 = fmaxf(m3, __shfl_xor(m3, off, 64));
    }

    // pass 2: weights lane-parallel, gather channel-parallel
    float den0, den1, den2, den3;
    float acc0, acc1, acc2, acc3;
    {
        float w0 = expf(e0 - m0), w1 = expf(e1 - m1);
        float w2 = expf(e2 - m2), w3 = expf(e3 - m3);
        den0 = (lane == 0) ? w0 : 0.f;
        den1 = (lane == 0) ? w1 : 0.f;
        den2 = (lane == 0) ? w2 : 0.f;
        den3 = (lane == 0) ? w3 : 0.f;
        float4 hv = h1v[(size_t)d * 64 + lane];
        acc0 = w0 * hv.x; acc1 = w1 * hv.y; acc2 = w2 * hv.z; acc3 = w3 * hv.w;
    }
    for (int c = beg; c < end; c += 64) {
        int rem = end - c; if (rem > 64) rem = 64;
        int sreg = 0;
        float w0r = 0.f, w1r = 0.f, w2r = 0.f, w3r = 0.f;
        if (lane < rem) {
            sreg = csr_src[c + lane];
            float4 a = asv[sreg];
            w0r = expf(lrelu(a.x + ad.x) - m0);
            w1r = expf(lrelu(a.y + ad.y) - m1);
            w2r = expf(lrelu(a.z + ad.z) - m2);
            w3r = expf(lrelu(a.w + ad.w) - m3);
            den0 += w0r; den1 += w1r; den2 += w2r; den3 += w3r;
        }
        for (int e = 0; e < rem; ++e) {
            int s = __shfl(sreg, e, 64);
            float w0 = __shfl(w0r, e, 64), w1 = __shfl(w1r, e, 64);
            float w2 = __shfl(w2r, e, 64), w3 = __shfl(w3r, e, 64);
            float4 hv = h1v[(size_t)s * 64 + lane];
            acc0 += w0 * hv.x; acc1 += w1 * hv.y;
            acc2 += w2 * hv.z; acc3 += w3 * hv.w;
        }
    }
#pragma unroll
    for (int off = 32; off; off >>= 1) {
        den0 += __shfl_xor(den0, off, 64);
        den1 += __shfl_xor(den1, off, 64);
        den2 += __shfl_xor(den2, off, 64);
        den3 += __shfl_xor(den3, off, 64);
    }
    float o0 = fmaxf(acc0 / (den0 + 1e-16f) + b1[lane], 0.f);
    float o1 = fmaxf(acc1 / (den1 + 1e-16f) + b1[64 + lane], 0.f);
    float o2 = fmaxf(acc2 / (den2 + 1e-16f) + b1[128 + lane], 0.f);
    float o3 = fmaxf(acc3 / (den3 + 1e-16f) + b1[192 + lane], 0.f);
    out1v[(size_t)d * 64 + lane] = make_float4(o0, o1, o2, o3);
}

// ---------------- Layer 2: out1@W2 (256->64) + attention logits ----------------
// input is PERMUTED: in[n*64+k] = float4 with channels c = {k, 64+k, 128+k, 192+k}
// Register-blocked: 8 nodes per wave iteration, k outer, to amortize LDS reads.
__global__ __launch_bounds__(256) void k_gemm2(const float4* __restrict__ in,
                                               const float* __restrict__ W2,
                                               const float* __restrict__ att_s2,
                                               const float* __restrict__ att_d2,
                                               float* __restrict__ h2,
                                               float* __restrict__ a_s2,
                                               float* __restrict__ a_d2) {
    __shared__ float Ws[256 * 64];  // 64 KB
    const int t = threadIdx.x;
    for (int i = t; i < 256 * 64; i += 256) Ws[i] = W2[i];
    __syncthreads();
    const int wave = t >> 6, lane = t & 63;
    const int n0 = blockIdx.x * 32 + wave * 8;
    if (n0 >= N_NODES) return;
    const int nn = min(8, N_NODES - n0);
    float acc[8] = {0.f, 0.f, 0.f, 0.f, 0.f, 0.f, 0.f, 0.f};
    const float4* base = in + (size_t)n0 * 64;
    if (nn == 8) {
#pragma unroll 2
        for (int k = 0; k < 64; ++k) {
            float w0 = Ws[k * 64 + lane];
            float w1 = Ws[(64 + k) * 64 + lane];
            float w2 = Ws[(128 + k) * 64 + lane];
            float w3 = Ws[(192 + k) * 64 + lane];
#pragma unroll
            for (int i = 0; i < 8; ++i) {
                float4 v = base[i * 64 + k];   // lane-uniform broadcast load
                acc[i] += v.x * w0 + v.y * w1 + v.z * w2 + v.w * w3;
            }
        }
    } else {
        for (int k = 0; k < 64; ++k) {
            float w0 = Ws[k * 64 + lane];
            float w1 = Ws[(64 + k) * 64 + lane];
            float w2 = Ws[(128 + k) * 64 + lane];
            float w3 = Ws[(192 + k) * 64 + lane];
            for (int i = 0; i < nn; ++i) {
                float4 v = base[i * 64 + k];
                acc[i] += v.x * w0 + v.y * w1 + v.z * w2 + v.w * w3;
            }
        }
    }
    const float asw = att_s2[lane], adw = att_d2[lane];
    for (int i = 0; i < nn; ++i) {
        const int n = n0 + i;
        const float a = acc[i];
        h2[(size_t)n * 64 + lane] = a;
        float vs = a * asw, vd = a * adw;
#pragma unroll
        for (int off = 32; off; off >>= 1) {
            vs += __shfl_xor(vs, off, 64);
            vd += __shfl_xor(vd, off, 64);
        }
        if (lane == 0) { a_s2[n] = vs; a_d2[n] = vd; }
    }
}

// ---------------- Layer 2 aggregation: wave per dst node ----------------
__global__ __launch_bounds__(256) void k_agg2(const float* __restrict__ h2,
                                              const float* __restrict__ as_,
                                              const float* __restrict__ ad_,
                                              const int* __restrict__ row_start,
                                              const int* __restrict__ csr_src,
                                              const float* __restrict__ b2,
                                              float* __restrict__ out2) {
    const int wave = threadIdx.x >> 6, lane = threadIdx.x & 63;
    const int d = blockIdx.x * 4 + wave;
    if (d >= N_NODES) return;
    const int beg = row_start[d], end = row_start[d + 1];
    const float adl = ad_[d];
    const float eself = lrelu(as_[d] + adl);

    float m = eself;
    for (int j = beg + lane; j < end; j += 64) {
        m = fmaxf(m, lrelu(as_[csr_src[j]] + adl));
    }
#pragma unroll
    for (int off = 32; off; off >>= 1) m = fmaxf(m, __shfl_xor(m, off, 64));

    float den, acc;
    {
        float w = expf(eself - m);
        den = (lane == 0) ? w : 0.f;
        acc = w * h2[(size_t)d * 64 + lane];
    }
    for (int c = beg; c < end; c += 64) {
        int rem = end - c; if (rem > 64) rem = 64;
        int sreg = 0;
        float wr = 0.f;
        if (lane < rem) {
            sreg = csr_src[c + lane];
            wr = expf(lrelu(as_[sreg] + adl) - m);
            den += wr;
        }
        for (int e = 0; e < rem; ++e) {
            int s = __shfl(sreg, e, 64);
            float w = __shfl(wr, e, 64);
            acc += w * h2[(size_t)s * 64 + lane];
        }
    }
#pragma unroll
    for (int off = 32; off; off >>= 1) den += __shfl_xor(den, off, 64);
    out2[(size_t)d * 64 + lane] = fmaxf(acc / (den + 1e-16f) + b2[lane], 0.f);
}

// ---------------- Global mean pool + linear ----------------
__global__ __launch_bounds__(256) void k_pool(const float* __restrict__ out2,
                                              const int* __restrict__ batch,
                                              const float* __restrict__ linW,
                                              const float* __restrict__ linb,
                                              float* __restrict__ out) {
    const int g = blockIdx.x;
    const int t = threadIdx.x, wave = t >> 6, lane = t & 63;
    __shared__ int s_beg, s_end;
    __shared__ float red[4][64];
    if (t == 0) {
        s_beg = lower_bound_i(batch, N_NODES, g);
        s_end = lower_bound_i(batch, N_NODES, g + 1);
    }
    __syncthreads();
    const int beg = s_beg, end = s_end;
    float sum = 0.f;
    for (int n = beg + wave; n < end; n += 4) sum += out2[(size_t)n * 64 + lane];
    red[wave][lane] = sum;
    __syncthreads();
    if (wave == 0) {
        float s = red[0][lane] + red[1][lane] + red[2][lane] + red[3][lane];
        float cnt = (float)(end - beg);
        red[0][lane] = s / fmaxf(cnt, 1.0f);
    }
    __syncthreads();
    if (t < 2) {
        float acc = linb[t];
        for (int c = 0; c < 64; ++c) acc += red[0][c] * linW[c * 2 + t];
        out[g * 2 + t] = acc;
    }
}

extern "C" void kernel_launch(void* const* d_in, const int* in_sizes, int n_in,
                              void* d_out, int out_size, void* d_ws, size_t ws_size,
                              hipStream_t stream) {
    const float* x    = (const float*)d_in[0];
    const int*   ei   = (const int*)d_in[1];
    const int*   bat  = (const int*)d_in[2];
    const float* W1   = (const float*)d_in[3];
    const float* as1  = (const float*)d_in[4];
    const float* ad1  = (const float*)d_in[5];
    const float* b1   = (const float*)d_in[6];
    const float* W2   = (const float*)d_in[7];
    const float* as2  = (const float*)d_in[8];
    const float* ad2  = (const float*)d_in[9];
    const float* b2   = (const float*)d_in[10];
    const float* linW = (const float*)d_in[11];
    const float* linb = (const float*)d_in[12];
    float* out = (float*)d_out;

    const int* src = ei;
    const int* dst = ei + N_EDGES;

    char* w = (char*)d_ws;
    float4* h1v  = (float4*)w; w += (size_t)N_NODES * 64 * 16;
    float4* out1 = (float4*)w; w += (size_t)N_NODES * 64 * 16;
    float4* a_s1 = (float4*)w; w += (size_t)N_NODES * 16;
    float4* a_d1 = (float4*)w; w += (size_t)N_NODES * 16;
    float* h2    = (float*)w; w += (size_t)N_NODES * 64 * 4;
    float* out2  = (float*)w; w += (size_t)N_NODES * 64 * 4;
    float* a_s2  = (float*)w; w += (size_t)N_NODES * 4;
    float* a_d2  = (float*)w; w += (size_t)N_NODES * 4;
    int* counts    = (int*)w; w += (size_t)N_NODES * 4;
    int* row_start = (int*)w; w += (size_t)(N_NODES + 64) * 4;
    int* cursor    = (int*)w; w += (size_t)N_NODES * 4;
    int* csr_src   = (int*)w; w += (size_t)N_EDGES * 4;

    // CSR build
    k_zero<<<(N_NODES + 255) / 256, 256, 0, stream>>>(counts, N_NODES);
    k_count<<<(N_EDGES + 255) / 256, 256, 0, stream>>>(dst, counts);
    k_scan<<<1, 256, 0, stream>>>(counts, row_start, cursor);
    k_fill<<<(N_EDGES + 255) / 256, 256, 0, stream>>>(src, dst, cursor, csr_src);

    // Layer 1
    k_gemm1<<<(N_NODES + 3) / 4, 256, 0, stream>>>(x, W1, as1, ad1, h1v, a_s1, a_d1);
    k_agg1<<<(N_NODES + 3) / 4, 256, 0, stream>>>(h1v, a_s1, a_d1, row_start, csr_src, b1, out1);
    // Layer 2
    k_gemm2<<<(N_NODES + 31) / 32, 256, 0, stream>>>(out1, W2, as2, ad2, h2, a_s2, a_d2);
    k_agg2<<<(N_NODES + 3) / 4, 256, 0, stream>>>(h2, a_s2, a_d2, row_start, csr_src, b2, out2);

    // Pool + linear
    k_pool<<<N_GRAPHS, 256, 0, stream>>>(out2, bat, linW, linb, out);
}

// Round 4
// 536.255 us; speedup vs baseline: 1.4182x; 1.1194x over previous
//
#include <hip/hip_runtime.h>
#include <math.h>

#define N_NODES 50000
#define N_EDGES 800000
#define N_GRAPHS 64
#define NEG_SLOPE 0.2f

__device__ __forceinline__ float lrelu(float x) { return x > 0.f ? x : NEG_SLOPE * x; }

__device__ __forceinline__ unsigned short f2bf(float f) {
    union { float f; unsigned int u; } v; v.f = f;
    unsigned int r = (v.u + 0x7fffu + ((v.u >> 16) & 1u)) >> 16;  // RNE
    return (unsigned short)r;
}
__device__ __forceinline__ float bf2f(unsigned short b) {
    union { unsigned int u; float f; } v; v.u = ((unsigned int)b) << 16;
    return v.f;
}

__device__ __forceinline__ int lower_bound_i(const int* __restrict__ a, int n, int v) {
    int lo = 0, hi = n;
    while (lo < hi) { int m = (lo + hi) >> 1; if (a[m] < v) lo = m + 1; else hi = m; }
    return lo;
}

// ---------------- CSR build ----------------
__global__ void k_zero(int* __restrict__ p, int n) {
    int i = blockIdx.x * blockDim.x + threadIdx.x;
    if (i < n) p[i] = 0;
}

__global__ void k_count(const int* __restrict__ dst, int* __restrict__ cnt) {
    int e = blockIdx.x * blockDim.x + threadIdx.x;
    if (e < N_EDGES) atomicAdd(&cnt[dst[e]], 1);
}

__global__ __launch_bounds__(256) void k_scan(const int* __restrict__ cnt,
                                              int* __restrict__ row_start,
                                              int* __restrict__ cursor) {
    __shared__ int tsum[256];
    __shared__ int total_s;
    const int t = threadIdx.x;
    const int chunk = (N_NODES + 255) / 256;
    int beg = t * chunk, end = min(N_NODES, beg + chunk);
    int s = 0;
    for (int i = beg; i < end; ++i) s += cnt[i];
    tsum[t] = s;
    __syncthreads();
    if (t == 0) {
        int run = 0;
        for (int j = 0; j < 256; ++j) { int v = tsum[j]; tsum[j] = run; run += v; }
        total_s = run;
    }
    __syncthreads();
    int run = tsum[t];
    for (int i = beg; i < end; ++i) {
        row_start[i] = run;
        cursor[i] = run;
        run += cnt[i];
    }
    if (t == 0) row_start[N_NODES] = total_s;
}

__global__ void k_fill(const int* __restrict__ src, const int* __restrict__ dst,
                       int* __restrict__ cursor, int* __restrict__ csr_src) {
    int e = blockIdx.x * blockDim.x + threadIdx.x;
    if (e < N_EDGES) {
        int d = dst[e];
        int p = atomicAdd(&cursor[d], 1);
        csr_src[p] = src[e];
    }
}

// ---------------- Layer 1: x@W1 (K=5) + attention logits ----------------
// h1 stored PERMUTED bf16: h1b[n*64 + ch] = ushort4(bf16 heads 0..3 at channel ch)
__global__ __launch_bounds__(256) void k_gemm1(const float* __restrict__ x,
                                               const float* __restrict__ W1,
                                               const float* __restrict__ att_s,
                                               const float* __restrict__ att_d,
                                               ushort4* __restrict__ h1b,
                                               float4* __restrict__ a_s,
                                               float4* __restrict__ a_d) {
    __shared__ float Ws[5 * 256];
    const int t = threadIdx.x;
    for (int i = t; i < 5 * 256; i += 256) Ws[i] = W1[i];
    __syncthreads();
    const int wave = t >> 6, lane = t & 63;
    const int n = blockIdx.x * 4 + wave;
    if (n >= N_NODES) return;
    float x0 = x[n * 5 + 0], x1 = x[n * 5 + 1], x2 = x[n * 5 + 2],
          x3 = x[n * 5 + 3], x4 = x[n * 5 + 4];
    float h[4], vs[4], vd[4];
#pragma unroll
    for (int hd = 0; hd < 4; ++hd) {
        const int c = hd * 64 + lane;
        h[hd] = x0 * Ws[c] + x1 * Ws[256 + c] + x2 * Ws[512 + c] +
                x3 * Ws[768 + c] + x4 * Ws[1024 + c];
        vs[hd] = h[hd] * att_s[c];
        vd[hd] = h[hd] * att_d[c];
    }
#pragma unroll
    for (int off = 32; off; off >>= 1) {
#pragma unroll
        for (int hd = 0; hd < 4; ++hd) {
            vs[hd] += __shfl_xor(vs[hd], off, 64);
            vd[hd] += __shfl_xor(vd[hd], off, 64);
        }
    }
    ushort4 hb;
    hb.x = f2bf(h[0]); hb.y = f2bf(h[1]); hb.z = f2bf(h[2]); hb.w = f2bf(h[3]);
    h1b[(size_t)n * 64 + lane] = hb;
    if (lane == 0) {
        a_s[n] = make_float4(vs[0], vs[1], vs[2], vs[3]);
        a_d[n] = make_float4(vd[0], vd[1], vd[2], vd[3]);
    }
}

// ---------------- Layer 1 aggregation: wave per dst node ----------------
__global__ __launch_bounds__(256) void k_agg1(const ushort4* __restrict__ h1b,
                                              const float4* __restrict__ asv,
                                              const float4* __restrict__ adv,
                                              const int* __restrict__ row_start,
                                              const int* __restrict__ csr_src,
                                              const float* __restrict__ b1,
                                              float4* __restrict__ out1v) {
    const int wave = threadIdx.x >> 6, lane = threadIdx.x & 63;
    const int d = blockIdx.x * 4 + wave;
    if (d >= N_NODES) return;
    const int beg = row_start[d], end = row_start[d + 1];
    const float4 ad = adv[d];
    const float4 as = asv[d];

    float e0 = lrelu(as.x + ad.x), e1 = lrelu(as.y + ad.y);
    float e2 = lrelu(as.z + ad.z), e3 = lrelu(as.w + ad.w);

    // pass 1: segment max, lane-parallel over edges
    float m0 = e0, m1 = e1, m2 = e2, m3 = e3;
    for (int j = beg + lane; j < end; j += 64) {
        int s = csr_src[j];
        float4 a = asv[s];
        m0 = fmaxf(m0, lrelu(a.x + ad.x));
        m1 = fmaxf(m1, lrelu(a.y + ad.y));
        m2 = fmaxf(m2, lrelu(a.z + ad.z));
        m3 = fmaxf(m3, lrelu(a.w + ad.w));
    }
#pragma unroll
    for (int off = 32; off; off >>= 1) {
        m0 = fmaxf(m0, __shfl_xor(m0, off, 64));
        m1 = fmaxf(m1, __shfl_xor(m1, off, 64));
        m2 = fmaxf(m2, __shfl_xor(m2, off, 64));
        m3 = fmaxf(m3, __shfl_xor(m3, off, 64));
    }

    // pass 2: weights lane-parallel, gather channel-parallel (bf16 payload)
    float den0, den1, den2, den3;
    float acc0, acc1, acc2, acc3;
    {
        float w0 = expf(e0 - m0), w1 = expf(e1 - m1);
        float w2 = expf(e2 - m2), w3 = expf(e3 - m3);
        den0 = (lane == 0) ? w0 : 0.f;
        den1 = (lane == 0) ? w1 : 0.f;
        den2 = (lane == 0) ? w2 : 0.f;
        den3 = (lane == 0) ? w3 : 0.f;
        ushort4 hv = h1b[(size_t)d * 64 + lane];
        acc0 = w0 * bf2f(hv.x); acc1 = w1 * bf2f(hv.y);
        acc2 = w2 * bf2f(hv.z); acc3 = w3 * bf2f(hv.w);
    }
    for (int c = beg; c < end; c += 64) {
        int rem = end - c; if (rem > 64) rem = 64;
        int sreg = 0;
        float w0r = 0.f, w1r = 0.f, w2r = 0.f, w3r = 0.f;
        if (lane < rem) {
            sreg = csr_src[c + lane];
            float4 a = asv[sreg];
            w0r = expf(lrelu(a.x + ad.x) - m0);
            w1r = expf(lrelu(a.y + ad.y) - m1);
            w2r = expf(lrelu(a.z + ad.z) - m2);
            w3r = expf(lrelu(a.w + ad.w) - m3);
            den0 += w0r; den1 += w1r; den2 += w2r; den3 += w3r;
        }
        int e = 0;
        for (; e + 4 <= rem; e += 4) {
            int s0 = __shfl(sreg, e, 64), s1 = __shfl(sreg, e + 1, 64);
            int s2 = __shfl(sreg, e + 2, 64), s3 = __shfl(sreg, e + 3, 64);
            ushort4 hv0 = h1b[(size_t)s0 * 64 + lane];
            ushort4 hv1 = h1b[(size_t)s1 * 64 + lane];
            ushort4 hv2 = h1b[(size_t)s2 * 64 + lane];
            ushort4 hv3 = h1b[(size_t)s3 * 64 + lane];
            float wa0 = __shfl(w0r, e, 64), wa1 = __shfl(w1r, e, 64);
            float wa2 = __shfl(w2r, e, 64), wa3 = __shfl(w3r, e, 64);
            acc0 += wa0 * bf2f(hv0.x); acc1 += wa1 * bf2f(hv0.y);
            acc2 += wa2 * bf2f(hv0.z); acc3 += wa3 * bf2f(hv0.w);
            float wb0 = __shfl(w0r, e + 1, 64), wb1 = __shfl(w1r, e + 1, 64);
            float wb2 = __shfl(w2r, e + 1, 64), wb3 = __shfl(w3r, e + 1, 64);
            acc0 += wb0 * bf2f(hv1.x); acc1 += wb1 * bf2f(hv1.y);
            acc2 += wb2 * bf2f(hv1.z); acc3 += wb3 * bf2f(hv1.w);
            float wc0 = __shfl(w0r, e + 2, 64), wc1 = __shfl(w1r, e + 2, 64);
            float wc2 = __shfl(w2r, e + 2, 64), wc3 = __shfl(w3r, e + 2, 64);
            acc0 += wc0 * bf2f(hv2.x); acc1 += wc1 * bf2f(hv2.y);
            acc2 += wc2 * bf2f(hv2.z); acc3 += wc3 * bf2f(hv2.w);
            float wd0 = __shfl(w0r, e + 3, 64), wd1 = __shfl(w1r, e + 3, 64);
            float wd2 = __shfl(w2r, e + 3, 64), wd3 = __shfl(w3r, e + 3, 64);
            acc0 += wd0 * bf2f(hv3.x); acc1 += wd1 * bf2f(hv3.y);
            acc2 += wd2 * bf2f(hv3.z); acc3 += wd3 * bf2f(hv3.w);
        }
        for (; e < rem; ++e) {
            int s = __shfl(sreg, e, 64);
            ushort4 hv = h1b[(size_t)s * 64 + lane];
            float w0 = __shfl(w0r, e, 64), w1 = __shfl(w1r, e, 64);
            float w2 = __shfl(w2r, e, 64), w3 = __shfl(w3r, e, 64);
            acc0 += w0 * bf2f(hv.x); acc1 += w1 * bf2f(hv.y);
            acc2 += w2 * bf2f(hv.z); acc3 += w3 * bf2f(hv.w);
        }
    }
#pragma unroll
    for (int off = 32; off; off >>= 1) {
        den0 += __shfl_xor(den0, off, 64);
        den1 += __shfl_xor(den1, off, 64);
        den2 += __shfl_xor(den2, off, 64);
        den3 += __shfl_xor(den3, off, 64);
    }
    float o0 = fmaxf(acc0 / (den0 + 1e-16f) + b1[lane], 0.f);
    float o1 = fmaxf(acc1 / (den1 + 1e-16f) + b1[64 + lane], 0.f);
    float o2 = fmaxf(acc2 / (den2 + 1e-16f) + b1[128 + lane], 0.f);
    float o3 = fmaxf(acc3 / (den3 + 1e-16f) + b1[192 + lane], 0.f);
    out1v[(size_t)d * 64 + lane] = make_float4(o0, o1, o2, o3);
}

// ---------------- Layer 2: out1@W2 (256->64) + attention logits ----------------
// input is PERMUTED: in[n*64+k] = float4 with channels c = {k, 64+k, 128+k, 192+k}
// Register-blocked: 8 nodes per wave, k outer. h2 written as bf16.
__global__ __launch_bounds__(256) void k_gemm2(const float4* __restrict__ in,
                                               const float* __restrict__ W2,
                                               const float* __restrict__ att_s2,
                                               const float* __restrict__ att_d2,
                                               unsigned short* __restrict__ h2b,
                                               float* __restrict__ a_s2,
                                               float* __restrict__ a_d2) {
    __shared__ float Ws[256 * 64];  // 64 KB
    const int t = threadIdx.x;
    for (int i = t; i < 256 * 64; i += 256) Ws[i] = W2[i];
    __syncthreads();
    const int wave = t >> 6, lane = t & 63;
    const int n0 = blockIdx.x * 32 + wave * 8;
    if (n0 >= N_NODES) return;
    const int nn = min(8, N_NODES - n0);
    float acc[8] = {0.f, 0.f, 0.f, 0.f, 0.f, 0.f, 0.f, 0.f};
    const float4* base = in + (size_t)n0 * 64;
    if (nn == 8) {
#pragma unroll 2
        for (int k = 0; k < 64; ++k) {
            float w0 = Ws[k * 64 + lane];
            float w1 = Ws[(64 + k) * 64 + lane];
            float w2 = Ws[(128 + k) * 64 + lane];
            float w3 = Ws[(192 + k) * 64 + lane];
#pragma unroll
            for (int i = 0; i < 8; ++i) {
                float4 v = base[i * 64 + k];   // lane-uniform broadcast load
                acc[i] += v.x * w0 + v.y * w1 + v.z * w2 + v.w * w3;
            }
        }
    } else {
        for (int k = 0; k < 64; ++k) {
            float w0 = Ws[k * 64 + lane];
            float w1 = Ws[(64 + k) * 64 + lane];
            float w2 = Ws[(128 + k) * 64 + lane];
            float w3 = Ws[(192 + k) * 64 + lane];
            for (int i = 0; i < nn; ++i) {
                float4 v = base[i * 64 + k];
                acc[i] += v.x * w0 + v.y * w1 + v.z * w2 + v.w * w3;
            }
        }
    }
    const float asw = att_s2[lane], adw = att_d2[lane];
    for (int i = 0; i < nn; ++i) {
        const int n = n0 + i;
        const float a = acc[i];
        h2b[(size_t)n * 64 + lane] = f2bf(a);
        float vs = a * asw, vd = a * adw;
#pragma unroll
        for (int off = 32; off; off >>= 1) {
            vs += __shfl_xor(vs, off, 64);
            vd += __shfl_xor(vd, off, 64);
        }
        if (lane == 0) { a_s2[n] = vs; a_d2[n] = vd; }
    }
}

// ---------------- Layer 2 aggregation: wave per dst node ----------------
__global__ __launch_bounds__(256) void k_agg2(const unsigned short* __restrict__ h2b,
                                              const float* __restrict__ as_,
                                              const float* __restrict__ ad_,
                                              const int* __restrict__ row_start,
                                              const int* __restrict__ csr_src,
                                              const float* __restrict__ b2,
                                              float* __restrict__ out2) {
    const int wave = threadIdx.x >> 6, lane = threadIdx.x & 63;
    const int d = blockIdx.x * 4 + wave;
    if (d >= N_NODES) return;
    const int beg = row_start[d], end = row_start[d + 1];
    const float adl = ad_[d];
    const float eself = lrelu(as_[d] + adl);

    float m = eself;
    for (int j = beg + lane; j < end; j += 64) {
        m = fmaxf(m, lrelu(as_[csr_src[j]] + adl));
    }
#pragma unroll
    for (int off = 32; off; off >>= 1) m = fmaxf(m, __shfl_xor(m, off, 64));

    float den, acc;
    {
        float w = expf(eself - m);
        den = (lane == 0) ? w : 0.f;
        acc = w * bf2f(h2b[(size_t)d * 64 + lane]);
    }
    for (int c = beg; c < end; c += 64) {
        int rem = end - c; if (rem > 64) rem = 64;
        int sreg = 0;
        float wr = 0.f;
        if (lane < rem) {
            sreg = csr_src[c + lane];
            wr = expf(lrelu(as_[sreg] + adl) - m);
            den += wr;
        }
        int e = 0;
        for (; e + 4 <= rem; e += 4) {
            int s0 = __shfl(sreg, e, 64), s1 = __shfl(sreg, e + 1, 64);
            int s2 = __shfl(sreg, e + 2, 64), s3 = __shfl(sreg, e + 3, 64);
            unsigned short v0 = h2b[(size_t)s0 * 64 + lane];
            unsigned short v1 = h2b[(size_t)s1 * 64 + lane];
            unsigned short v2 = h2b[(size_t)s2 * 64 + lane];
            unsigned short v3 = h2b[(size_t)s3 * 64 + lane];
            acc += __shfl(wr, e, 64) * bf2f(v0);
            acc += __shfl(wr, e + 1, 64) * bf2f(v1);
            acc += __shfl(wr, e + 2, 64) * bf2f(v2);
            acc += __shfl(wr, e + 3, 64) * bf2f(v3);
        }
        for (; e < rem; ++e) {
            int s = __shfl(sreg, e, 64);
            acc += __shfl(wr, e, 64) * bf2f(h2b[(size_t)s * 64 + lane]);
        }
    }
#pragma unroll
    for (int off = 32; off; off >>= 1) den += __shfl_xor(den, off, 64);
    out2[(size_t)d * 64 + lane] = fmaxf(acc / (den + 1e-16f) + b2[lane], 0.f);
}

// ---------------- Global mean pool + linear ----------------
__global__ __launch_bounds__(256) void k_pool(const float* __restrict__ out2,
                                              const int* __restrict__ batch,
                                              const float* __restrict__ linW,
                                              const float* __restrict__ linb,
                                              float* __restrict__ out) {
    const int g = blockIdx.x;
    const int t = threadIdx.x, wave = t >> 6, lane = t & 63;
    __shared__ int s_beg, s_end;
    __shared__ float red[4][64];
    if (t == 0) {
        s_beg = lower_bound_i(batch, N_NODES, g);
        s_end = lower_bound_i(batch, N_NODES, g + 1);
    }
    __syncthreads();
    const int beg = s_beg, end = s_end;
    float sum = 0.f;
    for (int n = beg + wave; n < end; n += 4) sum += out2[(size_t)n * 64 + lane];
    red[wave][lane] = sum;
    __syncthreads();
    if (wave == 0) {
        float s = red[0][lane] + red[1][lane] + red[2][lane] + red[3][lane];
        float cnt = (float)(end - beg);
        red[0][lane] = s / fmaxf(cnt, 1.0f);
    }
    __syncthreads();
    if (t < 2) {
        float acc = linb[t];
        for (int c = 0; c < 64; ++c) acc += red[0][c] * linW[c * 2 + t];
        out[g * 2 + t] = acc;
    }
}

extern "C" void kernel_launch(void* const* d_in, const int* in_sizes, int n_in,
                              void* d_out, int out_size, void* d_ws, size_t ws_size,
                              hipStream_t stream) {
    const float* x    = (const float*)d_in[0];
    const int*   ei   = (const int*)d_in[1];
    const int*   bat  = (const int*)d_in[2];
    const float* W1   = (const float*)d_in[3];
    const float* as1  = (const float*)d_in[4];
    const float* ad1  = (const float*)d_in[5];
    const float* b1   = (const float*)d_in[6];
    const float* W2   = (const float*)d_in[7];
    const float* as2  = (const float*)d_in[8];
    const float* ad2  = (const float*)d_in[9];
    const float* b2   = (const float*)d_in[10];
    const float* linW = (const float*)d_in[11];
    const float* linb = (const float*)d_in[12];
    float* out = (float*)d_out;

    const int* src = ei;
    const int* dst = ei + N_EDGES;

    char* w = (char*)d_ws;
    ushort4* h1b = (ushort4*)w; w += (size_t)N_NODES * 64 * 8;
    float4* out1 = (float4*)w; w += (size_t)N_NODES * 64 * 16;
    float4* a_s1 = (float4*)w; w += (size_t)N_NODES * 16;
    float4* a_d1 = (float4*)w; w += (size_t)N_NODES * 16;
    unsigned short* h2b = (unsigned short*)w; w += (size_t)N_NODES * 64 * 2;
    float* out2  = (float*)w; w += (size_t)N_NODES * 64 * 4;
    float* a_s2  = (float*)w; w += (size_t)N_NODES * 4;
    float* a_d2  = (float*)w; w += (size_t)N_NODES * 4;
    int* counts    = (int*)w; w += (size_t)N_NODES * 4;
    int* row_start = (int*)w; w += (size_t)(N_NODES + 64) * 4;
    int* cursor    = (int*)w; w += (size_t)N_NODES * 4;
    int* csr_src   = (int*)w; w += (size_t)N_EDGES * 4;

    // CSR build
    k_zero<<<(N_NODES + 255) / 256, 256, 0, stream>>>(counts, N_NODES);
    k_count<<<(N_EDGES + 255) / 256, 256, 0, stream>>>(dst, counts);
    k_scan<<<1, 256, 0, stream>>>(counts, row_start, cursor);
    k_fill<<<(N_EDGES + 255) / 256, 256, 0, stream>>>(src, dst, cursor, csr_src);

    // Layer 1
    k_gemm1<<<(N_NODES + 3) / 4, 256, 0, stream>>>(x, W1, as1, ad1, h1b, a_s1, a_d1);
    k_agg1<<<(N_NODES + 3) / 4, 256, 0, stream>>>(h1b, a_s1, a_d1, row_start, csr_src, b1, out1);
    // Layer 2
    k_gemm2<<<(N_NODES + 31) / 32, 256, 0, stream>>>(out1, W2, as2, ad2, h2b, a_s2, a_d2);
    k_agg2<<<(N_NODES + 3) / 4, 256, 0, stream>>>(h2b, a_s2, a_d2, row_start, csr_src, b2, out2);

    // Pool + linear
    k_pool<<<N_GRAPHS, 256, 0, stream>>>(out2, bat, linW, linb, out);
}

// Round 5
// 408.472 us; speedup vs baseline: 1.8618x; 1.3128x over previous
//
#include <hip/hip_runtime.h>
#include <math.h>

#define N_NODES 50000
#define N_EDGES 800000
#define N_GRAPHS 64
#define NEG_SLOPE 0.2f
#define SCAN_BS 512
#define SCAN_NB ((N_NODES + SCAN_BS - 1) / SCAN_BS)   // 98

__device__ __forceinline__ float lrelu(float x) { return x > 0.f ? x : NEG_SLOPE * x; }

__device__ __forceinline__ unsigned short f2bf(float f) {
    union { float f; unsigned int u; } v; v.f = f;
    unsigned int r = (v.u + 0x7fffu + ((v.u >> 16) & 1u)) >> 16;  // RNE
    return (unsigned short)r;
}
__device__ __forceinline__ float bf2f(unsigned short b) {
    union { unsigned int u; float f; } v; v.u = ((unsigned int)b) << 16;
    return v.f;
}
__device__ __forceinline__ float bfLO(unsigned int u) {
    union { unsigned int u; float f; } v; v.u = u << 16;
    return v.f;
}
__device__ __forceinline__ float bfHI(unsigned int u) {
    union { unsigned int u; float f; } v; v.u = u & 0xffff0000u;
    return v.f;
}

__device__ __forceinline__ int lower_bound_i(const int* __restrict__ a, int n, int v) {
    int lo = 0, hi = n;
    while (lo < hi) { int m = (lo + hi) >> 1; if (a[m] < v) lo = m + 1; else hi = m; }
    return lo;
}

// ---------------- CSR build ----------------
__global__ void k_zero(int* __restrict__ p, int n) {
    int i = blockIdx.x * blockDim.x + threadIdx.x;
    if (i < n) p[i] = 0;
}

__global__ void k_count(const int* __restrict__ dst, int* __restrict__ cnt) {
    int e = blockIdx.x * blockDim.x + threadIdx.x;
    if (e < N_EDGES) atomicAdd(&cnt[dst[e]], 1);
}

// phase 1: per-block exclusive scan (wave shuffle + cross-wave LDS)
__global__ __launch_bounds__(SCAN_BS) void k_scan1(const int* __restrict__ cnt,
                                                   int* __restrict__ local_pref,
                                                   int* __restrict__ blk_sum) {
    const int t = threadIdx.x;
    const int gid = blockIdx.x * SCAN_BS + t;
    const int lane = t & 63, w = t >> 6;
    int v = (gid < N_NODES) ? cnt[gid] : 0;
    int x = v;
#pragma unroll
    for (int off = 1; off < 64; off <<= 1) {
        int y = __shfl_up(x, off, 64);
        if (lane >= off) x += y;
    }
    __shared__ int wsum[SCAN_BS / 64];
    __shared__ int wpre[SCAN_BS / 64];
    if (lane == 63) wsum[w] = x;
    __syncthreads();
    if (t == 0) {
        int run = 0;
#pragma unroll
        for (int i = 0; i < SCAN_BS / 64; ++i) { wpre[i] = run; run += wsum[i]; }
    }
    __syncthreads();
    int excl = x - v + wpre[w];
    if (gid < N_NODES) local_pref[gid] = excl;
    if (t == SCAN_BS - 1) blk_sum[blockIdx.x] = excl + v;
}

// phase 2: scan the 98 block sums (single 128-thread block)
__global__ __launch_bounds__(128) void k_scan2(const int* __restrict__ blk_sum,
                                               int* __restrict__ blk_base,
                                               int* __restrict__ row_start) {
    const int t = threadIdx.x;
    const int lane = t & 63;
    int v = (t < SCAN_NB) ? blk_sum[t] : 0;
    int x = v;
#pragma unroll
    for (int off = 1; off < 64; off <<= 1) {
        int y = __shfl_up(x, off, 64);
        if (lane >= off) x += y;
    }
    __shared__ int wsum0;
    if (t == 63) wsum0 = x;
    __syncthreads();
    int excl = x - v + ((t >= 64) ? wsum0 : 0);
    if (t < SCAN_NB) blk_base[t] = excl;
    if (t == 127) row_start[N_NODES] = excl + v;  // grand total
}

// phase 3: add block base, write row_start + cursor
__global__ __launch_bounds__(SCAN_BS) void k_scan3(const int* __restrict__ local_pref,
                                                   const int* __restrict__ blk_base,
                                                   int* __restrict__ row_start,
                                                   int* __restrict__ cursor) {
    const int gid = blockIdx.x * SCAN_BS + threadIdx.x;
    if (gid < N_NODES) {
        int r = local_pref[gid] + blk_base[blockIdx.x];
        row_start[gid] = r;
        cursor[gid] = r;
    }
}

__global__ void k_fill(const int* __restrict__ src, const int* __restrict__ dst,
                       int* __restrict__ cursor, int* __restrict__ csr_src) {
    int e = blockIdx.x * blockDim.x + threadIdx.x;
    if (e < N_EDGES) {
        int d = dst[e];
        int p = atomicAdd(&cursor[d], 1);
        csr_src[p] = src[e];
    }
}

// ---------------- Layer 1: x@W1 (K=5) + attention logits ----------------
// h1 stored PERMUTED bf16: h1b[n*64 + ch] = ushort4(bf16 heads 0..3 at channel ch)
__global__ __launch_bounds__(256) void k_gemm1(const float* __restrict__ x,
                                               const float* __restrict__ W1,
                                               const float* __restrict__ att_s,
                                               const float* __restrict__ att_d,
                                               ushort4* __restrict__ h1b,
                                               float4* __restrict__ a_s,
                                               float4* __restrict__ a_d) {
    __shared__ float Ws[5 * 256];
    const int t = threadIdx.x;
    for (int i = t; i < 5 * 256; i += 256) Ws[i] = W1[i];
    __syncthreads();
    const int wave = t >> 6, lane = t & 63;
    const int n = blockIdx.x * 4 + wave;
    if (n >= N_NODES) return;
    float x0 = x[n * 5 + 0], x1 = x[n * 5 + 1], x2 = x[n * 5 + 2],
          x3 = x[n * 5 + 3], x4 = x[n * 5 + 4];
    float h[4], vs[4], vd[4];
#pragma unroll
    for (int hd = 0; hd < 4; ++hd) {
        const int c = hd * 64 + lane;
        h[hd] = x0 * Ws[c] + x1 * Ws[256 + c] + x2 * Ws[512 + c] +
                x3 * Ws[768 + c] + x4 * Ws[1024 + c];
        vs[hd] = h[hd] * att_s[c];
        vd[hd] = h[hd] * att_d[c];
    }
#pragma unroll
    for (int off = 32; off; off >>= 1) {
#pragma unroll
        for (int hd = 0; hd < 4; ++hd) {
            vs[hd] += __shfl_xor(vs[hd], off, 64);
            vd[hd] += __shfl_xor(vd[hd], off, 64);
        }
    }
    ushort4 hb;
    hb.x = f2bf(h[0]); hb.y = f2bf(h[1]); hb.z = f2bf(h[2]); hb.w = f2bf(h[3]);
    h1b[(size_t)n * 64 + lane] = hb;
    if (lane == 0) {
        a_s[n] = make_float4(vs[0], vs[1], vs[2], vs[3]);
        a_d[n] = make_float4(vd[0], vd[1], vd[2], vd[3]);
    }
}

// ---------------- Layer 1 aggregation: wave per dst node ----------------
__global__ __launch_bounds__(256) void k_agg1(const ushort4* __restrict__ h1b,
                                              const float4* __restrict__ asv,
                                              const float4* __restrict__ adv,
                                              const int* __restrict__ row_start,
                                              const int* __restrict__ csr_src,
                                              const float* __restrict__ b1,
                                              ushort4* __restrict__ out1b) {
    const int wave = threadIdx.x >> 6, lane = threadIdx.x & 63;
    const int d = blockIdx.x * 4 + wave;
    if (d >= N_NODES) return;
    const int beg = row_start[d], end = row_start[d + 1];
    const float4 ad = adv[d];
    const float4 as = asv[d];

    float e0 = lrelu(as.x + ad.x), e1 = lrelu(as.y + ad.y);
    float e2 = lrelu(as.z + ad.z), e3 = lrelu(as.w + ad.w);

    // pass 1: segment max, lane-parallel over edges
    float m0 = e0, m1 = e1, m2 = e2, m3 = e3;
    for (int j = beg + lane; j < end; j += 64) {
        int s = csr_src[j];
        float4 a = asv[s];
        m0 = fmaxf(m0, lrelu(a.x + ad.x));
        m1 = fmaxf(m1, lrelu(a.y + ad.y));
        m2 = fmaxf(m2, lrelu(a.z + ad.z));
        m3 = fmaxf(m3, lrelu(a.w + ad.w));
    }
#pragma unroll
    for (int off = 32; off; off >>= 1) {
        m0 = fmaxf(m0, __shfl_xor(m0, off, 64));
        m1 = fmaxf(m1, __shfl_xor(m1, off, 64));
        m2 = fmaxf(m2, __shfl_xor(m2, off, 64));
        m3 = fmaxf(m3, __shfl_xor(m3, off, 64));
    }

    // pass 2: weights lane-parallel, gather channel-parallel (bf16 payload)
    float den0, den1, den2, den3;
    float acc0, acc1, acc2, acc3;
    {
        float w0 = expf(e0 - m0), w1 = expf(e1 - m1);
        float w2 = expf(e2 - m2), w3 = expf(e3 - m3);
        den0 = (lane == 0) ? w0 : 0.f;
        den1 = (lane == 0) ? w1 : 0.f;
        den2 = (lane == 0) ? w2 : 0.f;
        den3 = (lane == 0) ? w3 : 0.f;
        ushort4 hv = h1b[(size_t)d * 64 + lane];
        acc0 = w0 * bf2f(hv.x); acc1 = w1 * bf2f(hv.y);
        acc2 = w2 * bf2f(hv.z); acc3 = w3 * bf2f(hv.w);
    }
    for (int c = beg; c < end; c += 64) {
        int rem = end - c; if (rem > 64) rem = 64;
        int sreg = 0;
        float w0r = 0.f, w1r = 0.f, w2r = 0.f, w3r = 0.f;
        if (lane < rem) {
            sreg = csr_src[c + lane];
            float4 a = asv[sreg];
            w0r = expf(lrelu(a.x + ad.x) - m0);
            w1r = expf(lrelu(a.y + ad.y) - m1);
            w2r = expf(lrelu(a.z + ad.z) - m2);
            w3r = expf(lrelu(a.w + ad.w) - m3);
            den0 += w0r; den1 += w1r; den2 += w2r; den3 += w3r;
        }
        int e = 0;
        for (; e + 4 <= rem; e += 4) {
            int s0 = __shfl(sreg, e, 64), s1 = __shfl(sreg, e + 1, 64);
            int s2 = __shfl(sreg, e + 2, 64), s3 = __shfl(sreg, e + 3, 64);
            ushort4 hv0 = h1b[(size_t)s0 * 64 + lane];
            ushort4 hv1 = h1b[(size_t)s1 * 64 + lane];
            ushort4 hv2 = h1b[(size_t)s2 * 64 + lane];
            ushort4 hv3 = h1b[(size_t)s3 * 64 + lane];
            float wa0 = __shfl(w0r, e, 64), wa1 = __shfl(w1r, e, 64);
            float wa2 = __shfl(w2r, e, 64), wa3 = __shfl(w3r, e, 64);
            acc0 += wa0 * bf2f(hv0.x); acc1 += wa1 * bf2f(hv0.y);
            acc2 += wa2 * bf2f(hv0.z); acc3 += wa3 * bf2f(hv0.w);
            float wb0 = __shfl(w0r, e + 1, 64), wb1 = __shfl(w1r, e + 1, 64);
            float wb2 = __shfl(w2r, e + 1, 64), wb3 = __shfl(w3r, e + 1, 64);
            acc0 += wb0 * bf2f(hv1.x); acc1 += wb1 * bf2f(hv1.y);
            acc2 += wb2 * bf2f(hv1.z); acc3 += wb3 * bf2f(hv1.w);
            float wc0 = __shfl(w0r, e + 2, 64), wc1 = __shfl(w1r, e + 2, 64);
            float wc2 = __shfl(w2r, e + 2, 64), wc3 = __shfl(w3r, e + 2, 64);
            acc0 += wc0 * bf2f(hv2.x); acc1 += wc1 * bf2f(hv2.y);
            acc2 += wc2 * bf2f(hv2.z); acc3 += wc3 * bf2f(hv2.w);
            float wd0 = __shfl(w0r, e + 3, 64), wd1 = __shfl(w1r, e + 3, 64);
            float wd2 = __shfl(w2r, e + 3, 64), wd3 = __shfl(w3r, e + 3, 64);
            acc0 += wd0 * bf2f(hv3.x); acc1 += wd1 * bf2f(hv3.y);
            acc2 += wd2 * bf2f(hv3.z); acc3 += wd3 * bf2f(hv3.w);
        }
        for (; e < rem; ++e) {
            int s = __shfl(sreg, e, 64);
            ushort4 hv = h1b[(size_t)s * 64 + lane];
            float w0 = __shfl(w0r, e, 64), w1 = __shfl(w1r, e, 64);
            float w2 = __shfl(w2r, e, 64), w3 = __shfl(w3r, e, 64);
            acc0 += w0 * bf2f(hv.x); acc1 += w1 * bf2f(hv.y);
            acc2 += w2 * bf2f(hv.z); acc3 += w3 * bf2f(hv.w);
        }
    }
#pragma unroll
    for (int off = 32; off; off >>= 1) {
        den0 += __shfl_xor(den0, off, 64);
        den1 += __shfl_xor(den1, off, 64);
        den2 += __shfl_xor(den2, off, 64);
        den3 += __shfl_xor(den3, off, 64);
    }
    float o0 = fmaxf(acc0 / (den0 + 1e-16f) + b1[lane], 0.f);
    float o1 = fmaxf(acc1 / (den1 + 1e-16f) + b1[64 + lane], 0.f);
    float o2 = fmaxf(acc2 / (den2 + 1e-16f) + b1[128 + lane], 0.f);
    float o3 = fmaxf(acc3 / (den3 + 1e-16f) + b1[192 + lane], 0.f);
    ushort4 ob;
    ob.x = f2bf(o0); ob.y = f2bf(o1); ob.z = f2bf(o2); ob.w = f2bf(o3);
    out1b[(size_t)d * 64 + lane] = ob;
}

// ---------------- Layer 2: out1@W2 (256->64) + attention logits ----------------
// input PERMUTED bf16: out1b[n*64+c] = ushort4(ch c, 64+c, 128+c, 192+c)
// 512-thread blocks (8 waves), 8 nodes/wave register-blocked, uint4 loads (2 elems).
__global__ __launch_bounds__(512) void k_gemm2(const unsigned short* __restrict__ in,
                                               const float* __restrict__ W2,
                                               const float* __restrict__ att_s2,
                                               const float* __restrict__ att_d2,
                                               unsigned short* __restrict__ h2b,
                                               float* __restrict__ a_s2,
                                               float* __restrict__ a_d2) {
    __shared__ float Ws[256 * 64];  // 64 KB
    const int t = threadIdx.x;
    for (int i = t; i < 256 * 64; i += 512) Ws[i] = W2[i];
    __syncthreads();
    const int wave = t >> 6, lane = t & 63;
    const int n0 = blockIdx.x * 64 + wave * 8;
    if (n0 >= N_NODES) return;
    const int nn = min(8, N_NODES - n0);
    float acc[8] = {0.f, 0.f, 0.f, 0.f, 0.f, 0.f, 0.f, 0.f};
    if (nn == 8) {
        const uint4* base = (const uint4*)(in + (size_t)n0 * 256);  // 32 uint4 per node
#pragma unroll 2
        for (int j = 0; j < 32; ++j) {
            const int k = 2 * j;
            float wA0 = Ws[k * 64 + lane];
            float wA1 = Ws[(64 + k) * 64 + lane];
            float wA2 = Ws[(128 + k) * 64 + lane];
            float wA3 = Ws[(192 + k) * 64 + lane];
            float wB0 = Ws[(k + 1) * 64 + lane];
            float wB1 = Ws[(65 + k) * 64 + lane];
            float wB2 = Ws[(129 + k) * 64 + lane];
            float wB3 = Ws[(193 + k) * 64 + lane];
#pragma unroll
            for (int i = 0; i < 8; ++i) {
                uint4 v = base[i * 32 + j];   // lane-uniform broadcast load
                acc[i] += bfLO(v.x) * wA0 + bfHI(v.x) * wA1 +
                          bfLO(v.y) * wA2 + bfHI(v.y) * wA3 +
                          bfLO(v.z) * wB0 + bfHI(v.z) * wB1 +
                          bfLO(v.w) * wB2 + bfHI(v.w) * wB3;
            }
        }
    } else {
        const ushort4* base = (const ushort4*)(in + (size_t)n0 * 256);
        for (int k = 0; k < 64; ++k) {
            float w0 = Ws[k * 64 + lane];
            float w1 = Ws[(64 + k) * 64 + lane];
            float w2 = Ws[(128 + k) * 64 + lane];
            float w3 = Ws[(192 + k) * 64 + lane];
            for (int i = 0; i < nn; ++i) {
                ushort4 v = base[i * 64 + k];
                acc[i] += bf2f(v.x) * w0 + bf2f(v.y) * w1 +
                          bf2f(v.z) * w2 + bf2f(v.w) * w3;
            }
        }
    }
    const float asw = att_s2[lane], adw = att_d2[lane];
    for (int i = 0; i < nn; ++i) {
        const int n = n0 + i;
        const float a = acc[i];
        h2b[(size_t)n * 64 + lane] = f2bf(a);
        float vs = a * asw, vd = a * adw;
#pragma unroll
        for (int off = 32; off; off >>= 1) {
            vs += __shfl_xor(vs, off, 64);
            vd += __shfl_xor(vd, off, 64);
        }
        if (lane == 0) { a_s2[n] = vs; a_d2[n] = vd; }
    }
}

// ---------------- Layer 2 aggregation: wave per dst node ----------------
__global__ __launch_bounds__(256) void k_agg2(const unsigned short* __restrict__ h2b,
                                              const float* __restrict__ as_,
                                              const float* __restrict__ ad_,
                                              const int* __restrict__ row_start,
                                              const int* __restrict__ csr_src,
                                              const float* __restrict__ b2,
                                              float* __restrict__ out2) {
    const int wave = threadIdx.x >> 6, lane = threadIdx.x & 63;
    const int d = blockIdx.x * 4 + wave;
    if (d >= N_NODES) return;
    const int beg = row_start[d], end = row_start[d + 1];
    const float adl = ad_[d];
    const float eself = lrelu(as_[d] + adl);

    float m = eself;
    for (int j = beg + lane; j < end; j += 64) {
        m = fmaxf(m, lrelu(as_[csr_src[j]] + adl));
    }
#pragma unroll
    for (int off = 32; off; off >>= 1) m = fmaxf(m, __shfl_xor(m, off, 64));

    float den, acc;
    {
        float w = expf(eself - m);
        den = (lane == 0) ? w : 0.f;
        acc = w * bf2f(h2b[(size_t)d * 64 + lane]);
    }
    for (int c = beg; c < end; c += 64) {
        int rem = end - c; if (rem > 64) rem = 64;
        int sreg = 0;
        float wr = 0.f;
        if (lane < rem) {
            sreg = csr_src[c + lane];
            wr = expf(lrelu(as_[sreg] + adl) - m);
            den += wr;
        }
        int e = 0;
        for (; e + 4 <= rem; e += 4) {
            int s0 = __shfl(sreg, e, 64), s1 = __shfl(sreg, e + 1, 64);
            int s2 = __shfl(sreg, e + 2, 64), s3 = __shfl(sreg, e + 3, 64);
            unsigned short v0 = h2b[(size_t)s0 * 64 + lane];
            unsigned short v1 = h2b[(size_t)s1 * 64 + lane];
            unsigned short v2 = h2b[(size_t)s2 * 64 + lane];
            unsigned short v3 = h2b[(size_t)s3 * 64 + lane];
            acc += __shfl(wr, e, 64) * bf2f(v0);
            acc += __shfl(wr, e + 1, 64) * bf2f(v1);
            acc += __shfl(wr, e + 2, 64) * bf2f(v2);
            acc += __shfl(wr, e + 3, 64) * bf2f(v3);
        }
        for (; e < rem; ++e) {
            int s = __shfl(sreg, e, 64);
            acc += __shfl(wr, e, 64) * bf2f(h2b[(size_t)s * 64 + lane]);
        }
    }
#pragma unroll
    for (int off = 32; off; off >>= 1) den += __shfl_xor(den, off, 64);
    out2[(size_t)d * 64 + lane] = fmaxf(acc / (den + 1e-16f) + b2[lane], 0.f);
}

// ---------------- Global mean pool + linear ----------------
__global__ __launch_bounds__(256) void k_pool(const float* __restrict__ out2,
                                              const int* __restrict__ batch,
                                              const float* __restrict__ linW,
                                              const float* __restrict__ linb,
                                              float* __restrict__ out) {
    const int g = blockIdx.x;
    const int t = threadIdx.x, wave = t >> 6, lane = t & 63;
    __shared__ int s_beg, s_end;
    __shared__ float red[4][64];
    if (t == 0) {
        s_beg = lower_bound_i(batch, N_NODES, g);
        s_end = lower_bound_i(batch, N_NODES, g + 1);
    }
    __syncthreads();
    const int beg = s_beg, end = s_end;
    float sum = 0.f;
    for (int n = beg + wave; n < end; n += 4) sum += out2[(size_t)n * 64 + lane];
    red[wave][lane] = sum;
    __syncthreads();
    if (wave == 0) {
        float s = red[0][lane] + red[1][lane] + red[2][lane] + red[3][lane];
        float cnt = (float)(end - beg);
        red[0][lane] = s / fmaxf(cnt, 1.0f);
    }
    __syncthreads();
    if (t < 2) {
        float acc = linb[t];
        for (int c = 0; c < 64; ++c) acc += red[0][c] * linW[c * 2 + t];
        out[g * 2 + t] = acc;
    }
}

extern "C" void kernel_launch(void* const* d_in, const int* in_sizes, int n_in,
                              void* d_out, int out_size, void* d_ws, size_t ws_size,
                              hipStream_t stream) {
    const float* x    = (const float*)d_in[0];
    const int*   ei   = (const int*)d_in[1];
    const int*   bat  = (const int*)d_in[2];
    const float* W1   = (const float*)d_in[3];
    const float* as1  = (const float*)d_in[4];
    const float* ad1  = (const float*)d_in[5];
    const float* b1   = (const float*)d_in[6];
    const float* W2   = (const float*)d_in[7];
    const float* as2  = (const float*)d_in[8];
    const float* ad2  = (const float*)d_in[9];
    const float* b2   = (const float*)d_in[10];
    const float* linW = (const float*)d_in[11];
    const float* linb = (const float*)d_in[12];
    float* out = (float*)d_out;

    const int* src = ei;
    const int* dst = ei + N_EDGES;

    char* w = (char*)d_ws;
    ushort4* h1b  = (ushort4*)w; w += (size_t)N_NODES * 64 * 8;
    ushort4* out1b = (ushort4*)w; w += (size_t)N_NODES * 64 * 8;
    float4* a_s1 = (float4*)w; w += (size_t)N_NODES * 16;
    float4* a_d1 = (float4*)w; w += (size_t)N_NODES * 16;
    unsigned short* h2b = (unsigned short*)w; w += (size_t)N_NODES * 64 * 2;
    float* out2  = (float*)w; w += (size_t)N_NODES * 64 * 4;
    float* a_s2  = (float*)w; w += (size_t)N_NODES * 4;
    float* a_d2  = (float*)w; w += (size_t)N_NODES * 4;
    int* counts    = (int*)w; w += (size_t)N_NODES * 4;
    int* row_start = (int*)w; w += (size_t)(N_NODES + 64) * 4;
    int* cursor    = (int*)w; w += (size_t)N_NODES * 4;
    int* csr_src   = (int*)w; w += (size_t)N_EDGES * 4;
    int* blk_sum   = (int*)w; w += 128 * 4;
    int* blk_base  = (int*)w; w += 128 * 4;

    // CSR build (multi-block scan)
    k_zero<<<(N_NODES + 255) / 256, 256, 0, stream>>>(counts, N_NODES);
    k_count<<<(N_EDGES + 255) / 256, 256, 0, stream>>>(dst, counts);
    k_scan1<<<SCAN_NB, SCAN_BS, 0, stream>>>(counts, cursor, blk_sum);   // cursor holds local prefix
    k_scan2<<<1, 128, 0, stream>>>(blk_sum, blk_base, row_start);
    k_scan3<<<SCAN_NB, SCAN_BS, 0, stream>>>(cursor, blk_base, row_start, cursor);
    k_fill<<<(N_EDGES + 255) / 256, 256, 0, stream>>>(src, dst, cursor, csr_src);

    // Layer 1
    k_gemm1<<<(N_NODES + 3) / 4, 256, 0, stream>>>(x, W1, as1, ad1, h1b, a_s1, a_d1);
    k_agg1<<<(N_NODES + 3) / 4, 256, 0, stream>>>(h1b, a_s1, a_d1, row_start, csr_src, b1, out1b);
    // Layer 2
    k_gemm2<<<(N_NODES + 63) / 64, 512, 0, stream>>>((const unsigned short*)out1b, W2, as2, ad2,
                                                     h2b, a_s2, a_d2);
    k_agg2<<<(N_NODES + 3) / 4, 256, 0, stream>>>(h2b, a_s2, a_d2, row_start, csr_src, b2, out2);

    // Pool + linear
    k_pool<<<N_GRAPHS, 256, 0, stream>>>(out2, bat, linW, linb, out);
}

// Round 6
// 318.462 us; speedup vs baseline: 2.3880x; 1.2826x over previous
//
#include <hip/hip_runtime.h>
#include <math.h>

#define N_NODES 50000
#define N_EDGES 800000
#define N_GRAPHS 64
#define NEG_SLOPE 0.2f
#define SCAN_BS 512
#define SCAN_NB ((N_NODES + SCAN_BS - 1) / SCAN_BS)   // 98

typedef __attribute__((ext_vector_type(8))) short short8;
typedef __attribute__((ext_vector_type(4))) float f32x4;

__device__ __forceinline__ float lrelu(float x) { return x > 0.f ? x : NEG_SLOPE * x; }

__device__ __forceinline__ unsigned short f2bf(float f) {
    union { float f; unsigned int u; } v; v.f = f;
    unsigned int r = (v.u + 0x7fffu + ((v.u >> 16) & 1u)) >> 16;  // RNE
    return (unsigned short)r;
}
__device__ __forceinline__ float bf2f(unsigned short b) {
    union { unsigned int u; float f; } v; v.u = ((unsigned int)b) << 16;
    return v.f;
}

__device__ __forceinline__ int lower_bound_i(const int* __restrict__ a, int n, int v) {
    int lo = 0, hi = n;
    while (lo < hi) { int m = (lo + hi) >> 1; if (a[m] < v) lo = m + 1; else hi = m; }
    return lo;
}

// ---------------- CSR build ----------------
__global__ void k_zero(int* __restrict__ p, int n) {
    int i = blockIdx.x * blockDim.x + threadIdx.x;
    if (i < n) p[i] = 0;
}

__global__ void k_count(const int* __restrict__ dst, int* __restrict__ cnt) {
    int e = blockIdx.x * blockDim.x + threadIdx.x;
    if (e < N_EDGES) atomicAdd(&cnt[dst[e]], 1);
}

__global__ __launch_bounds__(SCAN_BS) void k_scan1(const int* __restrict__ cnt,
                                                   int* __restrict__ local_pref,
                                                   int* __restrict__ blk_sum) {
    const int t = threadIdx.x;
    const int gid = blockIdx.x * SCAN_BS + t;
    const int lane = t & 63, w = t >> 6;
    int v = (gid < N_NODES) ? cnt[gid] : 0;
    int x = v;
#pragma unroll
    for (int off = 1; off < 64; off <<= 1) {
        int y = __shfl_up(x, off, 64);
        if (lane >= off) x += y;
    }
    __shared__ int wsum[SCAN_BS / 64];
    __shared__ int wpre[SCAN_BS / 64];
    if (lane == 63) wsum[w] = x;
    __syncthreads();
    if (t == 0) {
        int run = 0;
#pragma unroll
        for (int i = 0; i < SCAN_BS / 64; ++i) { wpre[i] = run; run += wsum[i]; }
    }
    __syncthreads();
    int excl = x - v + wpre[w];
    if (gid < N_NODES) local_pref[gid] = excl;
    if (t == SCAN_BS - 1) blk_sum[blockIdx.x] = excl + v;
}

__global__ __launch_bounds__(128) void k_scan2(const int* __restrict__ blk_sum,
                                               int* __restrict__ blk_base,
                                               int* __restrict__ row_start) {
    const int t = threadIdx.x;
    const int lane = t & 63;
    int v = (t < SCAN_NB) ? blk_sum[t] : 0;
    int x = v;
#pragma unroll
    for (int off = 1; off < 64; off <<= 1) {
        int y = __shfl_up(x, off, 64);
        if (lane >= off) x += y;
    }
    __shared__ int wsum0;
    if (t == 63) wsum0 = x;
    __syncthreads();
    int excl = x - v + ((t >= 64) ? wsum0 : 0);
    if (t < SCAN_NB) blk_base[t] = excl;
    if (t == 127) row_start[N_NODES] = excl + v;  // grand total
}

__global__ __launch_bounds__(SCAN_BS) void k_scan3(const int* __restrict__ local_pref,
                                                   const int* __restrict__ blk_base,
                                                   int* __restrict__ row_start,
                                                   int* __restrict__ cursor) {
    const int gid = blockIdx.x * SCAN_BS + threadIdx.x;
    if (gid < N_NODES) {
        int r = local_pref[gid] + blk_base[blockIdx.x];
        row_start[gid] = r;
        cursor[gid] = r;
    }
}

__global__ void k_fill(const int* __restrict__ src, const int* __restrict__ dst,
                       int* __restrict__ cursor, int* __restrict__ csr_src) {
    int e = blockIdx.x * blockDim.x + threadIdx.x;
    if (e < N_EDGES) {
        int d = dst[e];
        int p = atomicAdd(&cursor[d], 1);
        csr_src[p] = src[e];
    }
}

// ---------------- Layer 1: x@W1 (K=5) + attention logits ----------------
// h1 stored PERMUTED bf16: h1b[n*64 + ch] = ushort4(bf16 heads 0..3 at channel ch)
__global__ __launch_bounds__(256) void k_gemm1(const float* __restrict__ x,
                                               const float* __restrict__ W1,
                                               const float* __restrict__ att_s,
                                               const float* __restrict__ att_d,
                                               ushort4* __restrict__ h1b,
                                               float4* __restrict__ a_s,
                                               float4* __restrict__ a_d) {
    __shared__ float Ws[5 * 256];
    const int t = threadIdx.x;
    for (int i = t; i < 5 * 256; i += 256) Ws[i] = W1[i];
    __syncthreads();
    const int wave = t >> 6, lane = t & 63;
    const int n = blockIdx.x * 4 + wave;
    if (n >= N_NODES) return;
    float x0 = x[n * 5 + 0], x1 = x[n * 5 + 1], x2 = x[n * 5 + 2],
          x3 = x[n * 5 + 3], x4 = x[n * 5 + 4];
    float h[4], vs[4], vd[4];
#pragma unroll
    for (int hd = 0; hd < 4; ++hd) {
        const int c = hd * 64 + lane;
        h[hd] = x0 * Ws[c] + x1 * Ws[256 + c] + x2 * Ws[512 + c] +
                x3 * Ws[768 + c] + x4 * Ws[1024 + c];
        vs[hd] = h[hd] * att_s[c];
        vd[hd] = h[hd] * att_d[c];
    }
#pragma unroll
    for (int off = 32; off; off >>= 1) {
#pragma unroll
        for (int hd = 0; hd < 4; ++hd) {
            vs[hd] += __shfl_xor(vs[hd], off, 64);
            vd[hd] += __shfl_xor(vd[hd], off, 64);
        }
    }
    ushort4 hb;
    hb.x = f2bf(h[0]); hb.y = f2bf(h[1]); hb.z = f2bf(h[2]); hb.w = f2bf(h[3]);
    h1b[(size_t)n * 64 + lane] = hb;
    if (lane == 0) {
        a_s[n] = make_float4(vs[0], vs[1], vs[2], vs[3]);
        a_d[n] = make_float4(vd[0], vd[1], vd[2], vd[3]);
    }
}

// ---------------- Layer 1 aggregation: wave per dst node ----------------
// Output: out1 ROW-MAJOR bf16 [node][256], channel k = head*64 + ch
__global__ __launch_bounds__(256) void k_agg1(const ushort4* __restrict__ h1b,
                                              const float4* __restrict__ asv,
                                              const float4* __restrict__ adv,
                                              const int* __restrict__ row_start,
                                              const int* __restrict__ csr_src,
                                              const float* __restrict__ b1,
                                              unsigned short* __restrict__ out1rm) {
    const int wave = threadIdx.x >> 6, lane = threadIdx.x & 63;
    const int d = blockIdx.x * 4 + wave;
    if (d >= N_NODES) return;
    const int beg = row_start[d], end = row_start[d + 1];
    const float4 ad = adv[d];
    const float4 as = asv[d];

    float e0 = lrelu(as.x + ad.x), e1 = lrelu(as.y + ad.y);
    float e2 = lrelu(as.z + ad.z), e3 = lrelu(as.w + ad.w);

    // pass 1: segment max, lane-parallel over edges
    float m0 = e0, m1 = e1, m2 = e2, m3 = e3;
    for (int j = beg + lane; j < end; j += 64) {
        int s = csr_src[j];
        float4 a = asv[s];
        m0 = fmaxf(m0, lrelu(a.x + ad.x));
        m1 = fmaxf(m1, lrelu(a.y + ad.y));
        m2 = fmaxf(m2, lrelu(a.z + ad.z));
        m3 = fmaxf(m3, lrelu(a.w + ad.w));
    }
#pragma unroll
    for (int off = 32; off; off >>= 1) {
        m0 = fmaxf(m0, __shfl_xor(m0, off, 64));
        m1 = fmaxf(m1, __shfl_xor(m1, off, 64));
        m2 = fmaxf(m2, __shfl_xor(m2, off, 64));
        m3 = fmaxf(m3, __shfl_xor(m3, off, 64));
    }

    // pass 2: weights lane-parallel, gather channel-parallel (bf16 payload)
    float den0, den1, den2, den3;
    float acc0, acc1, acc2, acc3;
    {
        float w0 = expf(e0 - m0), w1 = expf(e1 - m1);
        float w2 = expf(e2 - m2), w3 = expf(e3 - m3);
        den0 = (lane == 0) ? w0 : 0.f;
        den1 = (lane == 0) ? w1 : 0.f;
        den2 = (lane == 0) ? w2 : 0.f;
        den3 = (lane == 0) ? w3 : 0.f;
        ushort4 hv = h1b[(size_t)d * 64 + lane];
        acc0 = w0 * bf2f(hv.x); acc1 = w1 * bf2f(hv.y);
        acc2 = w2 * bf2f(hv.z); acc3 = w3 * bf2f(hv.w);
    }
    for (int c = beg; c < end; c += 64) {
        int rem = end - c; if (rem > 64) rem = 64;
        int sreg = 0;
        float w0r = 0.f, w1r = 0.f, w2r = 0.f, w3r = 0.f;
        if (lane < rem) {
            sreg = csr_src[c + lane];
            float4 a = asv[sreg];
            w0r = expf(lrelu(a.x + ad.x) - m0);
            w1r = expf(lrelu(a.y + ad.y) - m1);
            w2r = expf(lrelu(a.z + ad.z) - m2);
            w3r = expf(lrelu(a.w + ad.w) - m3);
            den0 += w0r; den1 += w1r; den2 += w2r; den3 += w3r;
        }
        int e = 0;
        for (; e + 4 <= rem; e += 4) {
            int s0 = __shfl(sreg, e, 64), s1 = __shfl(sreg, e + 1, 64);
            int s2 = __shfl(sreg, e + 2, 64), s3 = __shfl(sreg, e + 3, 64);
            ushort4 hv0 = h1b[(size_t)s0 * 64 + lane];
            ushort4 hv1 = h1b[(size_t)s1 * 64 + lane];
            ushort4 hv2 = h1b[(size_t)s2 * 64 + lane];
            ushort4 hv3 = h1b[(size_t)s3 * 64 + lane];
            float wa0 = __shfl(w0r, e, 64), wa1 = __shfl(w1r, e, 64);
            float wa2 = __shfl(w2r, e, 64), wa3 = __shfl(w3r, e, 64);
            acc0 += wa0 * bf2f(hv0.x); acc1 += wa1 * bf2f(hv0.y);
            acc2 += wa2 * bf2f(hv0.z); acc3 += wa3 * bf2f(hv0.w);
            float wb0 = __shfl(w0r, e + 1, 64), wb1 = __shfl(w1r, e + 1, 64);
            float wb2 = __shfl(w2r, e + 1, 64), wb3 = __shfl(w3r, e + 1, 64);
            acc0 += wb0 * bf2f(hv1.x); acc1 += wb1 * bf2f(hv1.y);
            acc2 += wb2 * bf2f(hv1.z); acc3 += wb3 * bf2f(hv1.w);
            float wc0 = __shfl(w0r, e + 2, 64), wc1 = __shfl(w1r, e + 2, 64);
            float wc2 = __shfl(w2r, e + 2, 64), wc3 = __shfl(w3r, e + 2, 64);
            acc0 += wc0 * bf2f(hv2.x); acc1 += wc1 * bf2f(hv2.y);
            acc2 += wc2 * bf2f(hv2.z); acc3 += wc3 * bf2f(hv2.w);
            float wd0 = __shfl(w0r, e + 3, 64), wd1 = __shfl(w1r, e + 3, 64);
            float wd2 = __shfl(w2r, e + 3, 64), wd3 = __shfl(w3r, e + 3, 64);
            acc0 += wd0 * bf2f(hv3.x); acc1 += wd1 * bf2f(hv3.y);
            acc2 += wd2 * bf2f(hv3.z); acc3 += wd3 * bf2f(hv3.w);
        }
        for (; e < rem; ++e) {
            int s = __shfl(sreg, e, 64);
            ushort4 hv = h1b[(size_t)s * 64 + lane];
            float w0 = __shfl(w0r, e, 64), w1 = __shfl(w1r, e, 64);
            float w2 = __shfl(w2r, e, 64), w3 = __shfl(w3r, e, 64);
            acc0 += w0 * bf2f(hv.x); acc1 += w1 * bf2f(hv.y);
            acc2 += w2 * bf2f(hv.z); acc3 += w3 * bf2f(hv.w);
        }
    }
#pragma unroll
    for (int off = 32; off; off >>= 1) {
        den0 += __shfl_xor(den0, off, 64);
        den1 += __shfl_xor(den1, off, 64);
        den2 += __shfl_xor(den2, off, 64);
        den3 += __shfl_xor(den3, off, 64);
    }
    unsigned short* op = out1rm + (size_t)d * 256;
    op[lane]       = f2bf(fmaxf(acc0 / (den0 + 1e-16f) + b1[lane], 0.f));
    op[64 + lane]  = f2bf(fmaxf(acc1 / (den1 + 1e-16f) + b1[64 + lane], 0.f));
    op[128 + lane] = f2bf(fmaxf(acc2 / (den2 + 1e-16f) + b1[128 + lane], 0.f));
    op[192 + lane] = f2bf(fmaxf(acc3 / (den3 + 1e-16f) + b1[192 + lane], 0.f));
}

// ---------------- Layer 2: MFMA GEMM (50000x256 @ 256x64) + attention logits ----
// A = out1 row-major bf16. W2 pre-permuted into LDS bf16 so each B-frag is one
// ds_read_b128. A/B use the SAME (lane-group,reg)->k bijection so the result is
// layout-correct for any hardware k order (operand symmetry). C/D mapping is the
// HW-verified col=lane&15, row=(lane>>4)*4+reg.
__global__ __launch_bounds__(256) void k_gemm2(const unsigned short* __restrict__ in,
                                               const float* __restrict__ W2,
                                               const float* __restrict__ att_s2,
                                               const float* __restrict__ att_d2,
                                               unsigned short* __restrict__ h2b,
                                               float* __restrict__ a_s2,
                                               float* __restrict__ a_d2) {
    __shared__ unsigned short lW[16384];  // 32 KB: [s][g][t][c16][j]
    const int t = threadIdx.x;
    for (int idx = t; idx < 16384; idx += 256) {
        int j = idx & 7, c16 = (idx >> 3) & 15, tt = (idx >> 7) & 3,
            g = (idx >> 9) & 3, s = idx >> 11;
        int k = 32 * s + 8 * g + j, c = 16 * tt + c16;
        lW[idx] = f2bf(W2[k * 64 + c]);
    }
    __syncthreads();
    const int wave = t >> 6, lane = t & 63;
    const int g = lane >> 4, c16 = lane & 15;
    const int nb = blockIdx.x * 64 + wave * 16;
    if (nb >= N_NODES) return;

    f32x4 acc[4];
#pragma unroll
    for (int i = 0; i < 4; ++i) acc[i] = (f32x4){0.f, 0.f, 0.f, 0.f};

    const unsigned short* arow = in + (size_t)(nb + c16) * 256;  // A row = lane&15
#pragma unroll
    for (int s = 0; s < 8; ++s) {
        short8 a = *reinterpret_cast<const short8*>(arow + 32 * s + 8 * g);
#pragma unroll
        for (int tt = 0; tt < 4; ++tt) {
            short8 b = *reinterpret_cast<const short8*>(
                lW + ((((s * 4 + g) * 4 + tt) * 16 + c16) << 3));
            acc[tt] = __builtin_amdgcn_mfma_f32_16x16x32_bf16(a, b, acc[tt], 0, 0, 0);
        }
    }

    // Epilogue: D row r=(g*4+reg)=node offset, col=16*tt+c16=channel.
    float attS[4], attD[4];
#pragma unroll
    for (int tt = 0; tt < 4; ++tt) {
        attS[tt] = att_s2[16 * tt + c16];
        attD[tt] = att_d2[16 * tt + c16];
    }
#pragma unroll
    for (int r = 0; r < 4; ++r) {
        const int node = nb + g * 4 + r;
        const bool ok = node < N_NODES;
        float vs = 0.f, vd = 0.f;
#pragma unroll
        for (int tt = 0; tt < 4; ++tt) {
            float v = acc[tt][r];
            if (ok) h2b[(size_t)node * 64 + 16 * tt + c16] = f2bf(v);
            vs += v * attS[tt];
            vd += v * attD[tt];
        }
#pragma unroll
        for (int off = 1; off < 16; off <<= 1) {
            vs += __shfl_xor(vs, off, 64);
            vd += __shfl_xor(vd, off, 64);
        }
        if (ok && c16 == 0) { a_s2[node] = vs; a_d2[node] = vd; }
    }
}

// ---------------- Layer 2 aggregation: wave per dst node ----------------
__global__ __launch_bounds__(256) void k_agg2(const unsigned short* __restrict__ h2b,
                                              const float* __restrict__ as_,
                                              const float* __restrict__ ad_,
                                              const int* __restrict__ row_start,
                                              const int* __restrict__ csr_src,
                                              const float* __restrict__ b2,
                                              float* __restrict__ out2) {
    const int wave = threadIdx.x >> 6, lane = threadIdx.x & 63;
    const int d = blockIdx.x * 4 + wave;
    if (d >= N_NODES) return;
    const int beg = row_start[d], end = row_start[d + 1];
    const float adl = ad_[d];
    const float eself = lrelu(as_[d] + adl);

    float m = eself;
    for (int j = beg + lane; j < end; j += 64) {
        m = fmaxf(m, lrelu(as_[csr_src[j]] + adl));
    }
#pragma unroll
    for (int off = 32; off; off >>= 1) m = fmaxf(m, __shfl_xor(m, off, 64));

    float den, acc;
    {
        float w = expf(eself - m);
        den = (lane == 0) ? w : 0.f;
        acc = w * bf2f(h2b[(size_t)d * 64 + lane]);
    }
    for (int c = beg; c < end; c += 64) {
        int rem = end - c; if (rem > 64) rem = 64;
        int sreg = 0;
        float wr = 0.f;
        if (lane < rem) {
            sreg = csr_src[c + lane];
            wr = expf(lrelu(as_[sreg] + adl) - m);
            den += wr;
        }
        int e = 0;
        for (; e + 4 <= rem; e += 4) {
            int s0 = __shfl(sreg, e, 64), s1 = __shfl(sreg, e + 1, 64);
            int s2 = __shfl(sreg, e + 2, 64), s3 = __shfl(sreg, e + 3, 64);
            unsigned short v0 = h2b[(size_t)s0 * 64 + lane];
            unsigned short v1 = h2b[(size_t)s1 * 64 + lane];
            unsigned short v2 = h2b[(size_t)s2 * 64 + lane];
            unsigned short v3 = h2b[(size_t)s3 * 64 + lane];
            acc += __shfl(wr, e, 64) * bf2f(v0);
            acc += __shfl(wr, e + 1, 64) * bf2f(v1);
            acc += __shfl(wr, e + 2, 64) * bf2f(v2);
            acc += __shfl(wr, e + 3, 64) * bf2f(v3);
        }
        for (; e < rem; ++e) {
            int s = __shfl(sreg, e, 64);
            acc += __shfl(wr, e, 64) * bf2f(h2b[(size_t)s * 64 + lane]);
        }
    }
#pragma unroll
    for (int off = 32; off; off >>= 1) den += __shfl_xor(den, off, 64);
    out2[(size_t)d * 64 + lane] = fmaxf(acc / (den + 1e-16f) + b2[lane], 0.f);
}

// ---------------- Global mean pool + linear ----------------
__global__ __launch_bounds__(256) void k_pool(const float* __restrict__ out2,
                                              const int* __restrict__ batch,
                                              const float* __restrict__ linW,
                                              const float* __restrict__ linb,
                                              float* __restrict__ out) {
    const int g = blockIdx.x;
    const int t = threadIdx.x, wave = t >> 6, lane = t & 63;
    __shared__ int s_beg, s_end;
    __shared__ float red[4][64];
    if (t == 0) {
        s_beg = lower_bound_i(batch, N_NODES, g);
        s_end = lower_bound_i(batch, N_NODES, g + 1);
    }
    __syncthreads();
    const int beg = s_beg, end = s_end;
    float sum = 0.f;
    for (int n = beg + wave; n < end; n += 4) sum += out2[(size_t)n * 64 + lane];
    red[wave][lane] = sum;
    __syncthreads();
    if (wave == 0) {
        float s = red[0][lane] + red[1][lane] + red[2][lane] + red[3][lane];
        float cnt = (float)(end - beg);
        red[0][lane] = s / fmaxf(cnt, 1.0f);
    }
    __syncthreads();
    if (t < 2) {
        float acc = linb[t];
        for (int c = 0; c < 64; ++c) acc += red[0][c] * linW[c * 2 + t];
        out[g * 2 + t] = acc;
    }
}

extern "C" void kernel_launch(void* const* d_in, const int* in_sizes, int n_in,
                              void* d_out, int out_size, void* d_ws, size_t ws_size,
                              hipStream_t stream) {
    const float* x    = (const float*)d_in[0];
    const int*   ei   = (const int*)d_in[1];
    const int*   bat  = (const int*)d_in[2];
    const float* W1   = (const float*)d_in[3];
    const float* as1  = (const float*)d_in[4];
    const float* ad1  = (const float*)d_in[5];
    const float* b1   = (const float*)d_in[6];
    const float* W2   = (const float*)d_in[7];
    const float* as2  = (const float*)d_in[8];
    const float* ad2  = (const float*)d_in[9];
    const float* b2   = (const float*)d_in[10];
    const float* linW = (const float*)d_in[11];
    const float* linb = (const float*)d_in[12];
    float* out = (float*)d_out;

    const int* src = ei;
    const int* dst = ei + N_EDGES;

    char* w = (char*)d_ws;
    ushort4* h1b   = (ushort4*)w; w += (size_t)N_NODES * 64 * 8;
    unsigned short* out1rm = (unsigned short*)w; w += (size_t)N_NODES * 256 * 2;
    float4* a_s1 = (float4*)w; w += (size_t)N_NODES * 16;
    float4* a_d1 = (float4*)w; w += (size_t)N_NODES * 16;
    unsigned short* h2b = (unsigned short*)w; w += (size_t)N_NODES * 64 * 2;
    float* out2  = (float*)w; w += (size_t)N_NODES * 64 * 4;
    float* a_s2  = (float*)w; w += (size_t)N_NODES * 4;
    float* a_d2  = (float*)w; w += (size_t)N_NODES * 4;
    int* counts    = (int*)w; w += (size_t)N_NODES * 4;
    int* row_start = (int*)w; w += (size_t)(N_NODES + 64) * 4;
    int* cursor    = (int*)w; w += (size_t)N_NODES * 4;
    int* csr_src   = (int*)w; w += (size_t)N_EDGES * 4;
    int* blk_sum   = (int*)w; w += 128 * 4;
    int* blk_base  = (int*)w; w += 128 * 4;

    // CSR build (multi-block scan)
    k_zero<<<(N_NODES + 255) / 256, 256, 0, stream>>>(counts, N_NODES);
    k_count<<<(N_EDGES + 255) / 256, 256, 0, stream>>>(dst, counts);
    k_scan1<<<SCAN_NB, SCAN_BS, 0, stream>>>(counts, cursor, blk_sum);
    k_scan2<<<1, 128, 0, stream>>>(blk_sum, blk_base, row_start);
    k_scan3<<<SCAN_NB, SCAN_BS, 0, stream>>>(cursor, blk_base, row_start, cursor);
    k_fill<<<(N_EDGES + 255) / 256, 256, 0, stream>>>(src, dst, cursor, csr_src);

    // Layer 1
    k_gemm1<<<(N_NODES + 3) / 4, 256, 0, stream>>>(x, W1, as1, ad1, h1b, a_s1, a_d1);
    k_agg1<<<(N_NODES + 3) / 4, 256, 0, stream>>>(h1b, a_s1, a_d1, row_start, csr_src, b1, out1rm);
    // Layer 2 (MFMA)
    k_gemm2<<<(N_NODES + 63) / 64, 256, 0, stream>>>(out1rm, W2, as2, ad2, h2b, a_s2, a_d2);
    k_agg2<<<(N_NODES + 3) / 4, 256, 0, stream>>>(h2b, a_s2, a_d2, row_start, csr_src, b2, out2);

    // Pool + linear
    k_pool<<<N_GRAPHS, 256, 0, stream>>>(out2, bat, linW, linb, out);
}

// Round 7
// 311.535 us; speedup vs baseline: 2.4411x; 1.0222x over previous
//
#include <hip/hip_runtime.h>
#include <math.h>

#define N_NODES 50000
#define N_EDGES 800000
#define N_GRAPHS 64
#define NEG_SLOPE 0.2f
#define SCAN_BS 512
#define SCAN_NB ((N_NODES + SCAN_BS - 1) / SCAN_BS)   // 98

typedef __attribute__((ext_vector_type(8))) short short8;
typedef __attribute__((ext_vector_type(4))) float f32x4;

__device__ __forceinline__ float lrelu(float x) { return x > 0.f ? x : NEG_SLOPE * x; }

__device__ __forceinline__ unsigned short f2bf(float f) {
    union { float f; unsigned int u; } v; v.f = f;
    unsigned int r = (v.u + 0x7fffu + ((v.u >> 16) & 1u)) >> 16;  // RNE
    return (unsigned short)r;
}
__device__ __forceinline__ float bf2f(unsigned short b) {
    union { unsigned int u; float f; } v; v.u = ((unsigned int)b) << 16;
    return v.f;
}

__device__ __forceinline__ int lower_bound_i(const int* __restrict__ a, int n, int v) {
    int lo = 0, hi = n;
    while (lo < hi) { int m = (lo + hi) >> 1; if (a[m] < v) lo = m + 1; else hi = m; }
    return lo;
}

// ---------------- CSR build ----------------
__global__ void k_count(const int* __restrict__ dst, int* __restrict__ cnt) {
    int e = blockIdx.x * blockDim.x + threadIdx.x;
    if (e < N_EDGES) atomicAdd(&cnt[dst[e]], 1);
}

__global__ __launch_bounds__(SCAN_BS) void k_scan1(const int* __restrict__ cnt,
                                                   int* __restrict__ local_pref,
                                                   int* __restrict__ blk_sum) {
    const int t = threadIdx.x;
    const int gid = blockIdx.x * SCAN_BS + t;
    const int lane = t & 63, w = t >> 6;
    int v = (gid < N_NODES) ? cnt[gid] : 0;
    int x = v;
#pragma unroll
    for (int off = 1; off < 64; off <<= 1) {
        int y = __shfl_up(x, off, 64);
        if (lane >= off) x += y;
    }
    __shared__ int wsum[SCAN_BS / 64];
    __shared__ int wpre[SCAN_BS / 64];
    if (lane == 63) wsum[w] = x;
    __syncthreads();
    if (t == 0) {
        int run = 0;
#pragma unroll
        for (int i = 0; i < SCAN_BS / 64; ++i) { wpre[i] = run; run += wsum[i]; }
    }
    __syncthreads();
    int excl = x - v + wpre[w];
    if (gid < N_NODES) local_pref[gid] = excl;
    if (t == SCAN_BS - 1) blk_sum[blockIdx.x] = excl + v;
}

__global__ __launch_bounds__(128) void k_scan2(const int* __restrict__ blk_sum,
                                               int* __restrict__ blk_base,
                                               int* __restrict__ row_start) {
    const int t = threadIdx.x;
    const int lane = t & 63;
    int v = (t < SCAN_NB) ? blk_sum[t] : 0;
    int x = v;
#pragma unroll
    for (int off = 1; off < 64; off <<= 1) {
        int y = __shfl_up(x, off, 64);
        if (lane >= off) x += y;
    }
    __shared__ int wsum0;
    if (t == 63) wsum0 = x;
    __syncthreads();
    int excl = x - v + ((t >= 64) ? wsum0 : 0);
    if (t < SCAN_NB) blk_base[t] = excl;
    if (t == 127) row_start[N_NODES] = excl + v;  // grand total
}

__global__ __launch_bounds__(SCAN_BS) void k_scan3(const int* __restrict__ local_pref,
                                                   const int* __restrict__ blk_base,
                                                   int* __restrict__ row_start,
                                                   int* __restrict__ cursor) {
    const int gid = blockIdx.x * SCAN_BS + threadIdx.x;
    if (gid < N_NODES) {
        int r = local_pref[gid] + blk_base[blockIdx.x];
        row_start[gid] = r;
        cursor[gid] = r;
    }
}

__global__ void k_fill(const int* __restrict__ src, const int* __restrict__ dst,
                       int* __restrict__ cursor, int* __restrict__ csr_src) {
    int e = blockIdx.x * blockDim.x + threadIdx.x;
    if (e < N_EDGES) {
        int d = dst[e];
        int p = atomicAdd(&cursor[d], 1);
        csr_src[p] = src[e];
    }
}

// ---------------- Layer 1: x@W1 (K=5) + attention logits ----------------
// h1 stored PERMUTED bf16: h1b[n*64 + ch] = ushort4(bf16 heads 0..3 at channel ch)
__global__ __launch_bounds__(256) void k_gemm1(const float* __restrict__ x,
                                               const float* __restrict__ W1,
                                               const float* __restrict__ att_s,
                                               const float* __restrict__ att_d,
                                               ushort4* __restrict__ h1b,
                                               float4* __restrict__ a_s,
                                               float4* __restrict__ a_d) {
    __shared__ float Ws[5 * 256];
    const int t = threadIdx.x;
    for (int i = t; i < 5 * 256; i += 256) Ws[i] = W1[i];
    __syncthreads();
    const int wave = t >> 6, lane = t & 63;
    const int n = blockIdx.x * 4 + wave;
    if (n >= N_NODES) return;
    float x0 = x[n * 5 + 0], x1 = x[n * 5 + 1], x2 = x[n * 5 + 2],
          x3 = x[n * 5 + 3], x4 = x[n * 5 + 4];
    float h[4], vs[4], vd[4];
#pragma unroll
    for (int hd = 0; hd < 4; ++hd) {
        const int c = hd * 64 + lane;
        h[hd] = x0 * Ws[c] + x1 * Ws[256 + c] + x2 * Ws[512 + c] +
                x3 * Ws[768 + c] + x4 * Ws[1024 + c];
        vs[hd] = h[hd] * att_s[c];
        vd[hd] = h[hd] * att_d[c];
    }
#pragma unroll
    for (int off = 32; off; off >>= 1) {
#pragma unroll
        for (int hd = 0; hd < 4; ++hd) {
            vs[hd] += __shfl_xor(vs[hd], off, 64);
            vd[hd] += __shfl_xor(vd[hd], off, 64);
        }
    }
    ushort4 hb;
    hb.x = f2bf(h[0]); hb.y = f2bf(h[1]); hb.z = f2bf(h[2]); hb.w = f2bf(h[3]);
    h1b[(size_t)n * 64 + lane] = hb;
    if (lane == 0) {
        a_s[n] = make_float4(vs[0], vs[1], vs[2], vs[3]);
        a_d[n] = make_float4(vd[0], vd[1], vd[2], vd[3]);
    }
}

// ---------------- Layer 1 aggregation: wave per dst node ----------------
// Softmax computed WITHOUT max subtraction (shift-invariant; logits bounded ~|3|).
// Output: out1 ROW-MAJOR bf16 [node][256], channel k = head*64 + ch
__global__ __launch_bounds__(256) void k_agg1(const ushort4* __restrict__ h1b,
                                              const float4* __restrict__ asv,
                                              const float4* __restrict__ adv,
                                              const int* __restrict__ row_start,
                                              const int* __restrict__ csr_src,
                                              const float* __restrict__ b1,
                                              unsigned short* __restrict__ out1rm) {
    const int wave = threadIdx.x >> 6, lane = threadIdx.x & 63;
    const int d = blockIdx.x * 4 + wave;
    if (d >= N_NODES) return;
    const int beg = row_start[d], end = row_start[d + 1];
    const float4 ad = adv[d];
    const float4 as = asv[d];

    float den0, den1, den2, den3;
    float acc0, acc1, acc2, acc3;
    {   // self loop
        float w0 = __expf(lrelu(as.x + ad.x));
        float w1 = __expf(lrelu(as.y + ad.y));
        float w2 = __expf(lrelu(as.z + ad.z));
        float w3 = __expf(lrelu(as.w + ad.w));
        den0 = (lane == 0) ? w0 : 0.f;
        den1 = (lane == 0) ? w1 : 0.f;
        den2 = (lane == 0) ? w2 : 0.f;
        den3 = (lane == 0) ? w3 : 0.f;
        ushort4 hv = h1b[(size_t)d * 64 + lane];
        acc0 = w0 * bf2f(hv.x); acc1 = w1 * bf2f(hv.y);
        acc2 = w2 * bf2f(hv.z); acc3 = w3 * bf2f(hv.w);
    }
    for (int c = beg; c < end; c += 64) {
        int rem = end - c; if (rem > 64) rem = 64;
        int sreg = 0;
        float w0r = 0.f, w1r = 0.f, w2r = 0.f, w3r = 0.f;
        if (lane < rem) {
            sreg = csr_src[c + lane];
            float4 a = asv[sreg];
            w0r = __expf(lrelu(a.x + ad.x));
            w1r = __expf(lrelu(a.y + ad.y));
            w2r = __expf(lrelu(a.z + ad.z));
            w3r = __expf(lrelu(a.w + ad.w));
            den0 += w0r; den1 += w1r; den2 += w2r; den3 += w3r;
        }
        int e = 0;
        for (; e + 8 <= rem; e += 8) {
            int sq[8];
#pragma unroll
            for (int q = 0; q < 8; ++q) sq[q] = __shfl(sreg, e + q, 64);
            ushort4 hq[8];
#pragma unroll
            for (int q = 0; q < 8; ++q) hq[q] = h1b[(size_t)sq[q] * 64 + lane];
#pragma unroll
            for (int q = 0; q < 8; ++q) {
                float a0 = __shfl(w0r, e + q, 64), a1 = __shfl(w1r, e + q, 64);
                float a2 = __shfl(w2r, e + q, 64), a3 = __shfl(w3r, e + q, 64);
                acc0 += a0 * bf2f(hq[q].x); acc1 += a1 * bf2f(hq[q].y);
                acc2 += a2 * bf2f(hq[q].z); acc3 += a3 * bf2f(hq[q].w);
            }
        }
        for (; e < rem; ++e) {
            int s = __shfl(sreg, e, 64);
            ushort4 hv = h1b[(size_t)s * 64 + lane];
            float a0 = __shfl(w0r, e, 64), a1 = __shfl(w1r, e, 64);
            float a2 = __shfl(w2r, e, 64), a3 = __shfl(w3r, e, 64);
            acc0 += a0 * bf2f(hv.x); acc1 += a1 * bf2f(hv.y);
            acc2 += a2 * bf2f(hv.z); acc3 += a3 * bf2f(hv.w);
        }
    }
#pragma unroll
    for (int off = 32; off; off >>= 1) {
        den0 += __shfl_xor(den0, off, 64);
        den1 += __shfl_xor(den1, off, 64);
        den2 += __shfl_xor(den2, off, 64);
        den3 += __shfl_xor(den3, off, 64);
    }
    unsigned short* op = out1rm + (size_t)d * 256;
    op[lane]       = f2bf(fmaxf(acc0 / (den0 + 1e-16f) + b1[lane], 0.f));
    op[64 + lane]  = f2bf(fmaxf(acc1 / (den1 + 1e-16f) + b1[64 + lane], 0.f));
    op[128 + lane] = f2bf(fmaxf(acc2 / (den2 + 1e-16f) + b1[128 + lane], 0.f));
    op[192 + lane] = f2bf(fmaxf(acc3 / (den3 + 1e-16f) + b1[192 + lane], 0.f));
}

// ---------------- Layer 2: MFMA GEMM (50000x256 @ 256x64) + attention logits ----
__global__ __launch_bounds__(256) void k_gemm2(const unsigned short* __restrict__ in,
                                               const float* __restrict__ W2,
                                               const float* __restrict__ att_s2,
                                               const float* __restrict__ att_d2,
                                               unsigned short* __restrict__ h2b,
                                               float* __restrict__ a_s2,
                                               float* __restrict__ a_d2) {
    __shared__ unsigned short lW[16384];  // 32 KB: [s][g][t][c16][j]
    const int t = threadIdx.x;
    for (int idx = t; idx < 16384; idx += 256) {
        int j = idx & 7, c16 = (idx >> 3) & 15, tt = (idx >> 7) & 3,
            g = (idx >> 9) & 3, s = idx >> 11;
        int k = 32 * s + 8 * g + j, c = 16 * tt + c16;
        lW[idx] = f2bf(W2[k * 64 + c]);
    }
    __syncthreads();
    const int wave = t >> 6, lane = t & 63;
    const int g = lane >> 4, c16 = lane & 15;
    const int nb = blockIdx.x * 64 + wave * 16;
    if (nb >= N_NODES) return;

    f32x4 acc[4];
#pragma unroll
    for (int i = 0; i < 4; ++i) acc[i] = (f32x4){0.f, 0.f, 0.f, 0.f};

    const unsigned short* arow = in + (size_t)(nb + c16) * 256;  // A row = lane&15
#pragma unroll
    for (int s = 0; s < 8; ++s) {
        short8 a = *reinterpret_cast<const short8*>(arow + 32 * s + 8 * g);
#pragma unroll
        for (int tt = 0; tt < 4; ++tt) {
            short8 b = *reinterpret_cast<const short8*>(
                lW + ((((s * 4 + g) * 4 + tt) * 16 + c16) << 3));
            acc[tt] = __builtin_amdgcn_mfma_f32_16x16x32_bf16(a, b, acc[tt], 0, 0, 0);
        }
    }

    float attS[4], attD[4];
#pragma unroll
    for (int tt = 0; tt < 4; ++tt) {
        attS[tt] = att_s2[16 * tt + c16];
        attD[tt] = att_d2[16 * tt + c16];
    }
#pragma unroll
    for (int r = 0; r < 4; ++r) {
        const int node = nb + g * 4 + r;
        const bool ok = node < N_NODES;
        float vs = 0.f, vd = 0.f;
#pragma unroll
        for (int tt = 0; tt < 4; ++tt) {
            float v = acc[tt][r];
            if (ok) h2b[(size_t)node * 64 + 16 * tt + c16] = f2bf(v);
            vs += v * attS[tt];
            vd += v * attD[tt];
        }
#pragma unroll
        for (int off = 1; off < 16; off <<= 1) {
            vs += __shfl_xor(vs, off, 64);
            vd += __shfl_xor(vd, off, 64);
        }
        if (ok && c16 == 0) { a_s2[node] = vs; a_d2[node] = vd; }
    }
}

// ---------------- Layer 2 aggregation: wave per dst node (no-max softmax) -----
__global__ __launch_bounds__(256) void k_agg2(const unsigned short* __restrict__ h2b,
                                              const float* __restrict__ as_,
                                              const float* __restrict__ ad_,
                                              const int* __restrict__ row_start,
                                              const int* __restrict__ csr_src,
                                              const float* __restrict__ b2,
                                              float* __restrict__ out2) {
    const int wave = threadIdx.x >> 6, lane = threadIdx.x & 63;
    const int d = blockIdx.x * 4 + wave;
    if (d >= N_NODES) return;
    const int beg = row_start[d], end = row_start[d + 1];
    const float adl = ad_[d];

    float den, acc;
    {
        float w = __expf(lrelu(as_[d] + adl));
        den = (lane == 0) ? w : 0.f;
        acc = w * bf2f(h2b[(size_t)d * 64 + lane]);
    }
    for (int c = beg; c < end; c += 64) {
        int rem = end - c; if (rem > 64) rem = 64;
        int sreg = 0;
        float wr = 0.f;
        if (lane < rem) {
            sreg = csr_src[c + lane];
            wr = __expf(lrelu(as_[sreg] + adl));
            den += wr;
        }
        int e = 0;
        for (; e + 8 <= rem; e += 8) {
            int sq[8];
#pragma unroll
            for (int q = 0; q < 8; ++q) sq[q] = __shfl(sreg, e + q, 64);
            unsigned short vq[8];
#pragma unroll
            for (int q = 0; q < 8; ++q) vq[q] = h2b[(size_t)sq[q] * 64 + lane];
#pragma unroll
            for (int q = 0; q < 8; ++q) {
                acc += __shfl(wr, e + q, 64) * bf2f(vq[q]);
            }
        }
        for (; e < rem; ++e) {
            int s = __shfl(sreg, e, 64);
            acc += __shfl(wr, e, 64) * bf2f(h2b[(size_t)s * 64 + lane]);
        }
    }
#pragma unroll
    for (int off = 32; off; off >>= 1) den += __shfl_xor(den, off, 64);
    out2[(size_t)d * 64 + lane] = fmaxf(acc / (den + 1e-16f) + b2[lane], 0.f);
}

// ---------------- Global mean pool + linear ----------------
__global__ __launch_bounds__(256) void k_pool(const float* __restrict__ out2,
                                              const int* __restrict__ batch,
                                              const float* __restrict__ linW,
                                              const float* __restrict__ linb,
                                              float* __restrict__ out) {
    const int g = blockIdx.x;
    const int t = threadIdx.x, wave = t >> 6, lane = t & 63;
    __shared__ int s_beg, s_end;
    __shared__ float red[4][64];
    if (t == 0) {
        s_beg = lower_bound_i(batch, N_NODES, g);
        s_end = lower_bound_i(batch, N_NODES, g + 1);
    }
    __syncthreads();
    const int beg = s_beg, end = s_end;
    float sum = 0.f;
    for (int n = beg + wave; n < end; n += 4) sum += out2[(size_t)n * 64 + lane];
    red[wave][lane] = sum;
    __syncthreads();
    if (wave == 0) {
        float s = red[0][lane] + red[1][lane] + red[2][lane] + red[3][lane];
        float cnt = (float)(end - beg);
        red[0][lane] = s / fmaxf(cnt, 1.0f);
    }
    __syncthreads();
    if (t < 2) {
        float acc = linb[t];
        for (int c = 0; c < 64; ++c) acc += red[0][c] * linW[c * 2 + t];
        out[g * 2 + t] = acc;
    }
}

extern "C" void kernel_launch(void* const* d_in, const int* in_sizes, int n_in,
                              void* d_out, int out_size, void* d_ws, size_t ws_size,
                              hipStream_t stream) {
    const float* x    = (const float*)d_in[0];
    const int*   ei   = (const int*)d_in[1];
    const int*   bat  = (const int*)d_in[2];
    const float* W1   = (const float*)d_in[3];
    const float* as1  = (const float*)d_in[4];
    const float* ad1  = (const float*)d_in[5];
    const float* b1   = (const float*)d_in[6];
    const float* W2   = (const float*)d_in[7];
    const float* as2  = (const float*)d_in[8];
    const float* ad2  = (const float*)d_in[9];
    const float* b2   = (const float*)d_in[10];
    const float* linW = (const float*)d_in[11];
    const float* linb = (const float*)d_in[12];
    float* out = (float*)d_out;

    const int* src = ei;
    const int* dst = ei + N_EDGES;

    char* w = (char*)d_ws;
    ushort4* h1b   = (ushort4*)w; w += (size_t)N_NODES * 64 * 8;
    unsigned short* out1rm = (unsigned short*)w; w += (size_t)N_NODES * 256 * 2;
    float4* a_s1 = (float4*)w; w += (size_t)N_NODES * 16;
    float4* a_d1 = (float4*)w; w += (size_t)N_NODES * 16;
    unsigned short* h2b = (unsigned short*)w; w += (size_t)N_NODES * 64 * 2;
    float* out2  = (float*)w; w += (size_t)N_NODES * 64 * 4;
    float* a_s2  = (float*)w; w += (size_t)N_NODES * 4;
    float* a_d2  = (float*)w; w += (size_t)N_NODES * 4;
    int* counts    = (int*)w; w += (size_t)N_NODES * 4;
    int* row_start = (int*)w; w += (size_t)(N_NODES + 64) * 4;
    int* cursor    = (int*)w; w += (size_t)N_NODES * 4;
    int* csr_src   = (int*)w; w += (size_t)N_EDGES * 4;
    int* blk_sum   = (int*)w; w += 128 * 4;
    int* blk_base  = (int*)w; w += 128 * 4;

    // CSR build (multi-block scan)
    hipMemsetAsync(counts, 0, (size_t)N_NODES * 4, stream);
    k_count<<<(N_EDGES + 255) / 256, 256, 0, stream>>>(dst, counts);
    k_scan1<<<SCAN_NB, SCAN_BS, 0, stream>>>(counts, cursor, blk_sum);
    k_scan2<<<1, 128, 0, stream>>>(blk_sum, blk_base, row_start);
    k_scan3<<<SCAN_NB, SCAN_BS, 0, stream>>>(cursor, blk_base, row_start, cursor);
    k_fill<<<(N_EDGES + 255) / 256, 256, 0, stream>>>(src, dst, cursor, csr_src);

    // Layer 1
    k_gemm1<<<(N_NODES + 3) / 4, 256, 0, stream>>>(x, W1, as1, ad1, h1b, a_s1, a_d1);
    k_agg1<<<(N_NODES + 3) / 4, 256, 0, stream>>>(h1b, a_s1, a_d1, row_start, csr_src, b1, out1rm);
    // Layer 2 (MFMA)
    k_gemm2<<<(N_NODES + 63) / 64, 256, 0, stream>>>(out1rm, W2, as2, ad2, h2b, a_s2, a_d2);
    k_agg2<<<(N_NODES + 3) / 4, 256, 0, stream>>>(h2b, a_s2, a_d2, row_start, csr_src, b2, out2);

    // Pool + linear
    k_pool<<<N_GRAPHS, 256, 0, stream>>>(out2, bat, linW, linb, out);
}

// Round 8
// 288.503 us; speedup vs baseline: 2.6360x; 1.0798x over previous
//
#include <hip/hip_runtime.h>
#include <math.h>

#define N_NODES 50000
#define N_EDGES 800000
#define N_GRAPHS 64
#define NEG_SLOPE 0.2f
#define SCAN_BS 512
#define SCAN_NB ((N_NODES + SCAN_BS - 1) / SCAN_BS)   // 98

typedef __attribute__((ext_vector_type(8))) short short8;
typedef __attribute__((ext_vector_type(4))) float f32x4;

__device__ __forceinline__ float lrelu(float x) { return x > 0.f ? x : NEG_SLOPE * x; }

__device__ __forceinline__ unsigned short f2bf(float f) {
    union { float f; unsigned int u; } v; v.f = f;
    unsigned int r = (v.u + 0x7fffu + ((v.u >> 16) & 1u)) >> 16;  // RNE
    return (unsigned short)r;
}
__device__ __forceinline__ float bf2f(unsigned short b) {
    union { unsigned int u; float f; } v; v.u = ((unsigned int)b) << 16;
    return v.f;
}

__device__ __forceinline__ int lower_bound_i(const int* __restrict__ a, int n, int v) {
    int lo = 0, hi = n;
    while (lo < hi) { int m = (lo + hi) >> 1; if (a[m] < v) lo = m + 1; else hi = m; }
    return lo;
}

// ---------------- CSR build ----------------
__global__ void k_count(const int* __restrict__ dst, int* __restrict__ cnt) {
    int e = blockIdx.x * blockDim.x + threadIdx.x;
    if (e < N_EDGES) atomicAdd(&cnt[dst[e]], 1);
}

__global__ __launch_bounds__(SCAN_BS) void k_scan1(const int* __restrict__ cnt,
                                                   int* __restrict__ local_pref,
                                                   int* __restrict__ blk_sum) {
    const int t = threadIdx.x;
    const int gid = blockIdx.x * SCAN_BS + t;
    const int lane = t & 63, w = t >> 6;
    int v = (gid < N_NODES) ? cnt[gid] : 0;
    int x = v;
#pragma unroll
    for (int off = 1; off < 64; off <<= 1) {
        int y = __shfl_up(x, off, 64);
        if (lane >= off) x += y;
    }
    __shared__ int wsum[SCAN_BS / 64];
    __shared__ int wpre[SCAN_BS / 64];
    if (lane == 63) wsum[w] = x;
    __syncthreads();
    if (t == 0) {
        int run = 0;
#pragma unroll
        for (int i = 0; i < SCAN_BS / 64; ++i) { wpre[i] = run; run += wsum[i]; }
    }
    __syncthreads();
    int excl = x - v + wpre[w];
    if (gid < N_NODES) local_pref[gid] = excl;
    if (t == SCAN_BS - 1) blk_sum[blockIdx.x] = excl + v;
}

__global__ __launch_bounds__(128) void k_scan2(const int* __restrict__ blk_sum,
                                               int* __restrict__ blk_base,
                                               int* __restrict__ row_start) {
    const int t = threadIdx.x;
    const int lane = t & 63;
    int v = (t < SCAN_NB) ? blk_sum[t] : 0;
    int x = v;
#pragma unroll
    for (int off = 1; off < 64; off <<= 1) {
        int y = __shfl_up(x, off, 64);
        if (lane >= off) x += y;
    }
    __shared__ int wsum0;
    if (t == 63) wsum0 = x;
    __syncthreads();
    int excl = x - v + ((t >= 64) ? wsum0 : 0);
    if (t < SCAN_NB) blk_base[t] = excl;
    if (t == 127) row_start[N_NODES] = excl + v;  // grand total
}

__global__ __launch_bounds__(SCAN_BS) void k_scan3(const int* __restrict__ local_pref,
                                                   const int* __restrict__ blk_base,
                                                   int* __restrict__ row_start,
                                                   int* __restrict__ cursor) {
    const int gid = blockIdx.x * SCAN_BS + threadIdx.x;
    if (gid < N_NODES) {
        int r = local_pref[gid] + blk_base[blockIdx.x];
        row_start[gid] = r;
        cursor[gid] = r;
    }
}

__global__ void k_fill(const int* __restrict__ src, const int* __restrict__ dst,
                       int* __restrict__ cursor, int* __restrict__ csr_src) {
    int e = blockIdx.x * blockDim.x + threadIdx.x;
    if (e < N_EDGES) {
        int d = dst[e];
        int p = atomicAdd(&cursor[d], 1);
        csr_src[p] = src[e];
    }
}

// ---------------- Layer 1 logits: a_s/a_d per node (h1 NOT materialized) -----
__global__ __launch_bounds__(256) void k_gemm1(const float* __restrict__ x,
                                               const float* __restrict__ W1,
                                               const float* __restrict__ att_s,
                                               const float* __restrict__ att_d,
                                               float4* __restrict__ a_s,
                                               float4* __restrict__ a_d) {
    __shared__ float Ws[5 * 256];
    const int t = threadIdx.x;
    for (int i = t; i < 5 * 256; i += 256) Ws[i] = W1[i];
    __syncthreads();
    const int wave = t >> 6, lane = t & 63;
    const int n = blockIdx.x * 4 + wave;
    if (n >= N_NODES) return;
    float x0 = x[n * 5 + 0], x1 = x[n * 5 + 1], x2 = x[n * 5 + 2],
          x3 = x[n * 5 + 3], x4 = x[n * 5 + 4];
    float vs[4], vd[4];
#pragma unroll
    for (int hd = 0; hd < 4; ++hd) {
        const int c = hd * 64 + lane;
        float h = x0 * Ws[c] + x1 * Ws[256 + c] + x2 * Ws[512 + c] +
                  x3 * Ws[768 + c] + x4 * Ws[1024 + c];
        vs[hd] = h * att_s[c];
        vd[hd] = h * att_d[c];
    }
#pragma unroll
    for (int off = 32; off; off >>= 1) {
#pragma unroll
        for (int hd = 0; hd < 4; ++hd) {
            vs[hd] += __shfl_xor(vs[hd], off, 64);
            vd[hd] += __shfl_xor(vd[hd], off, 64);
        }
    }
    if (lane == 0) {
        a_s[n] = make_float4(vs[0], vs[1], vs[2], vs[3]);
        a_d[n] = make_float4(vd[0], vd[1], vd[2], vd[3]);
    }
}

// ---------------- Layer 1 aggregation: wave per dst node ----------------
// h1[src] RECOMPUTED per edge from x[src] (20 B, L2-resident) with W1 column in
// VGPRs. Per-edge scalars staged in LDS, re-read with uniform broadcast ds_reads.
// No-max softmax (logits bounded). Output row-major bf16 [node][256].
__global__ __launch_bounds__(256) void k_agg1(const float* __restrict__ x,
                                              const float* __restrict__ W1,
                                              const float4* __restrict__ asv,
                                              const float4* __restrict__ adv,
                                              const int* __restrict__ row_start,
                                              const int* __restrict__ csr_src,
                                              const float* __restrict__ b1,
                                              unsigned short* __restrict__ out1rm) {
    __shared__ float4 wq[4][64];
    __shared__ float4 xq[4][64];
    __shared__ float  xtl[4][64];
    const int wave = threadIdx.x >> 6, lane = threadIdx.x & 63;
    const int d = blockIdx.x * 4 + wave;
    if (d >= N_NODES) return;

    // W1 column for this lane: w1rH[i] = W1[i][H*64+lane]
    float w1r0[5], w1r1[5], w1r2[5], w1r3[5];
#pragma unroll
    for (int i = 0; i < 5; ++i) {
        w1r0[i] = W1[i * 256 + lane];
        w1r1[i] = W1[i * 256 + 64 + lane];
        w1r2[i] = W1[i * 256 + 128 + lane];
        w1r3[i] = W1[i * 256 + 192 + lane];
    }

    const int beg = row_start[d], end = row_start[d + 1];
    const float4 ad = adv[d];

    float den0, den1, den2, den3;
    float acc0, acc1, acc2, acc3;
    {   // self loop (all-uniform x[d] loads)
        float4 as = asv[d];
        float w0 = __expf(lrelu(as.x + ad.x));
        float w1 = __expf(lrelu(as.y + ad.y));
        float w2 = __expf(lrelu(as.z + ad.z));
        float w3 = __expf(lrelu(as.w + ad.w));
        den0 = (lane == 0) ? w0 : 0.f;
        den1 = (lane == 0) ? w1 : 0.f;
        den2 = (lane == 0) ? w2 : 0.f;
        den3 = (lane == 0) ? w3 : 0.f;
        const float* xp = x + (size_t)d * 5;
        float x0 = xp[0], x1 = xp[1], x2 = xp[2], x3 = xp[3], x4 = xp[4];
        float h0 = x0 * w1r0[0] + x1 * w1r0[1] + x2 * w1r0[2] + x3 * w1r0[3] + x4 * w1r0[4];
        float h1 = x0 * w1r1[0] + x1 * w1r1[1] + x2 * w1r1[2] + x3 * w1r1[3] + x4 * w1r1[4];
        float h2 = x0 * w1r2[0] + x1 * w1r2[1] + x2 * w1r2[2] + x3 * w1r2[3] + x4 * w1r2[4];
        float h3 = x0 * w1r3[0] + x1 * w1r3[1] + x2 * w1r3[2] + x3 * w1r3[3] + x4 * w1r3[4];
        acc0 = w0 * h0; acc1 = w1 * h1; acc2 = w2 * h2; acc3 = w3 * h3;
    }

    for (int c = beg; c < end; c += 64) {
        int rem = end - c; if (rem > 64) rem = 64;
        if (lane < rem) {   // batch phase: lane-parallel weights + x staging
            int s = csr_src[c + lane];
            float4 a = asv[s];
            float4 wv;
            wv.x = __expf(lrelu(a.x + ad.x));
            wv.y = __expf(lrelu(a.y + ad.y));
            wv.z = __expf(lrelu(a.z + ad.z));
            wv.w = __expf(lrelu(a.w + ad.w));
            den0 += wv.x; den1 += wv.y; den2 += wv.z; den3 += wv.w;
            wq[wave][lane] = wv;
            const float* xp = x + (size_t)s * 5;
            xq[wave][lane] = make_float4(xp[0], xp[1], xp[2], xp[3]);
            xtl[wave][lane] = xp[4];
        }
        // serial phase: uniform broadcast reads, h recomputed in registers
#pragma unroll 4
        for (int e = 0; e < rem; ++e) {
            float4 wv = wq[wave][e];
            float4 xv = xq[wave][e];
            float x4 = xtl[wave][e];
            float h0 = xv.x * w1r0[0] + xv.y * w1r0[1] + xv.z * w1r0[2] + xv.w * w1r0[3] + x4 * w1r0[4];
            float h1 = xv.x * w1r1[0] + xv.y * w1r1[1] + xv.z * w1r1[2] + xv.w * w1r1[3] + x4 * w1r1[4];
            float h2 = xv.x * w1r2[0] + xv.y * w1r2[1] + xv.z * w1r2[2] + xv.w * w1r2[3] + x4 * w1r2[4];
            float h3 = xv.x * w1r3[0] + xv.y * w1r3[1] + xv.z * w1r3[2] + xv.w * w1r3[3] + x4 * w1r3[4];
            acc0 += wv.x * h0; acc1 += wv.y * h1;
            acc2 += wv.z * h2; acc3 += wv.w * h3;
        }
    }
#pragma unroll
    for (int off = 32; off; off >>= 1) {
        den0 += __shfl_xor(den0, off, 64);
        den1 += __shfl_xor(den1, off, 64);
        den2 += __shfl_xor(den2, off, 64);
        den3 += __shfl_xor(den3, off, 64);
    }
    unsigned short* op = out1rm + (size_t)d * 256;
    op[lane]       = f2bf(fmaxf(acc0 / (den0 + 1e-16f) + b1[lane], 0.f));
    op[64 + lane]  = f2bf(fmaxf(acc1 / (den1 + 1e-16f) + b1[64 + lane], 0.f));
    op[128 + lane] = f2bf(fmaxf(acc2 / (den2 + 1e-16f) + b1[128 + lane], 0.f));
    op[192 + lane] = f2bf(fmaxf(acc3 / (den3 + 1e-16f) + b1[192 + lane], 0.f));
}

// ---------------- Layer 2: MFMA GEMM (50000x256 @ 256x64) + attention logits ----
__global__ __launch_bounds__(256) void k_gemm2(const unsigned short* __restrict__ in,
                                               const float* __restrict__ W2,
                                               const float* __restrict__ att_s2,
                                               const float* __restrict__ att_d2,
                                               unsigned short* __restrict__ h2b,
                                               float* __restrict__ a_s2,
                                               float* __restrict__ a_d2) {
    __shared__ unsigned short lW[16384];  // 32 KB: [s][g][t][c16][j]
    const int t = threadIdx.x;
    for (int idx = t; idx < 16384; idx += 256) {
        int j = idx & 7, c16 = (idx >> 3) & 15, tt = (idx >> 7) & 3,
            g = (idx >> 9) & 3, s = idx >> 11;
        int k = 32 * s + 8 * g + j, c = 16 * tt + c16;
        lW[idx] = f2bf(W2[k * 64 + c]);
    }
    __syncthreads();
    const int wave = t >> 6, lane = t & 63;
    const int g = lane >> 4, c16 = lane & 15;
    const int nb = blockIdx.x * 64 + wave * 16;
    if (nb >= N_NODES) return;

    f32x4 acc[4];
#pragma unroll
    for (int i = 0; i < 4; ++i) acc[i] = (f32x4){0.f, 0.f, 0.f, 0.f};

    const unsigned short* arow = in + (size_t)(nb + c16) * 256;  // A row = lane&15
#pragma unroll
    for (int s = 0; s < 8; ++s) {
        short8 a = *reinterpret_cast<const short8*>(arow + 32 * s + 8 * g);
#pragma unroll
        for (int tt = 0; tt < 4; ++tt) {
            short8 b = *reinterpret_cast<const short8*>(
                lW + ((((s * 4 + g) * 4 + tt) * 16 + c16) << 3));
            acc[tt] = __builtin_amdgcn_mfma_f32_16x16x32_bf16(a, b, acc[tt], 0, 0, 0);
        }
    }

    float attS[4], attD[4];
#pragma unroll
    for (int tt = 0; tt < 4; ++tt) {
        attS[tt] = att_s2[16 * tt + c16];
        attD[tt] = att_d2[16 * tt + c16];
    }
#pragma unroll
    for (int r = 0; r < 4; ++r) {
        const int node = nb + g * 4 + r;
        const bool ok = node < N_NODES;
        float vs = 0.f, vd = 0.f;
#pragma unroll
        for (int tt = 0; tt < 4; ++tt) {
            float v = acc[tt][r];
            if (ok) h2b[(size_t)node * 64 + 16 * tt + c16] = f2bf(v);
            vs += v * attS[tt];
            vd += v * attD[tt];
        }
#pragma unroll
        for (int off = 1; off < 16; off <<= 1) {
            vs += __shfl_xor(vs, off, 64);
            vd += __shfl_xor(vd, off, 64);
        }
        if (ok && c16 == 0) { a_s2[node] = vs; a_d2[node] = vd; }
    }
}

// ---------------- Layer 2 aggregation: wave per dst node (no-max softmax) -----
__global__ __launch_bounds__(256) void k_agg2(const unsigned short* __restrict__ h2b,
                                              const float* __restrict__ as_,
                                              const float* __restrict__ ad_,
                                              const int* __restrict__ row_start,
                                              const int* __restrict__ csr_src,
                                              const float* __restrict__ b2,
                                              float* __restrict__ out2) {
    const int wave = threadIdx.x >> 6, lane = threadIdx.x & 63;
    const int d = blockIdx.x * 4 + wave;
    if (d >= N_NODES) return;
    const int beg = row_start[d], end = row_start[d + 1];
    const float adl = ad_[d];

    float den, acc;
    {
        float w = __expf(lrelu(as_[d] + adl));
        den = (lane == 0) ? w : 0.f;
        acc = w * bf2f(h2b[(size_t)d * 64 + lane]);
    }
    for (int c = beg; c < end; c += 64) {
        int rem = end - c; if (rem > 64) rem = 64;
        int sreg = 0;
        float wr = 0.f;
        if (lane < rem) {
            sreg = csr_src[c + lane];
            wr = __expf(lrelu(as_[sreg] + adl));
            den += wr;
        }
        int e = 0;
        for (; e + 8 <= rem; e += 8) {
            int sq[8];
#pragma unroll
            for (int q = 0; q < 8; ++q) sq[q] = __shfl(sreg, e + q, 64);
            unsigned short vq[8];
#pragma unroll
            for (int q = 0; q < 8; ++q) vq[q] = h2b[(size_t)sq[q] * 64 + lane];
#pragma unroll
            for (int q = 0; q < 8; ++q) {
                acc += __shfl(wr, e + q, 64) * bf2f(vq[q]);
            }
        }
        for (; e < rem; ++e) {
            int s = __shfl(sreg, e, 64);
            acc += __shfl(wr, e, 64) * bf2f(h2b[(size_t)s * 64 + lane]);
        }
    }
#pragma unroll
    for (int off = 32; off; off >>= 1) den += __shfl_xor(den, off, 64);
    out2[(size_t)d * 64 + lane] = fmaxf(acc / (den + 1e-16f) + b2[lane], 0.f);
}

// ---------------- Global mean pool + linear ----------------
__global__ __launch_bounds__(256) void k_pool(const float* __restrict__ out2,
                                              const int* __restrict__ batch,
                                              const float* __restrict__ linW,
                                              const float* __restrict__ linb,
                                              float* __restrict__ out) {
    const int g = blockIdx.x;
    const int t = threadIdx.x, wave = t >> 6, lane = t & 63;
    __shared__ int s_beg, s_end;
    __shared__ float red[4][64];
    if (t == 0) {
        s_beg = lower_bound_i(batch, N_NODES, g);
        s_end = lower_bound_i(batch, N_NODES, g + 1);
    }
    __syncthreads();
    const int beg = s_beg, end = s_end;
    float sum = 0.f;
    for (int n = beg + wave; n < end; n += 4) sum += out2[(size_t)n * 64 + lane];
    red[wave][lane] = sum;
    __syncthreads();
    if (wave == 0) {
        float s = red[0][lane] + red[1][lane] + red[2][lane] + red[3][lane];
        float cnt = (float)(end - beg);
        red[0][lane] = s / fmaxf(cnt, 1.0f);
    }
    __syncthreads();
    if (t < 2) {
        float acc = linb[t];
        for (int c = 0; c < 64; ++c) acc += red[0][c] * linW[c * 2 + t];
        out[g * 2 + t] = acc;
    }
}

extern "C" void kernel_launch(void* const* d_in, const int* in_sizes, int n_in,
                              void* d_out, int out_size, void* d_ws, size_t ws_size,
                              hipStream_t stream) {
    const float* x    = (const float*)d_in[0];
    const int*   ei   = (const int*)d_in[1];
    const int*   bat  = (const int*)d_in[2];
    const float* W1   = (const float*)d_in[3];
    const float* as1  = (const float*)d_in[4];
    const float* ad1  = (const float*)d_in[5];
    const float* b1   = (const float*)d_in[6];
    const float* W2   = (const float*)d_in[7];
    const float* as2  = (const float*)d_in[8];
    const float* ad2  = (const float*)d_in[9];
    const float* b2   = (const float*)d_in[10];
    const float* linW = (const float*)d_in[11];
    const float* linb = (const float*)d_in[12];
    float* out = (float*)d_out;

    const int* src = ei;
    const int* dst = ei + N_EDGES;

    char* w = (char*)d_ws;
    unsigned short* out1rm = (unsigned short*)w; w += (size_t)N_NODES * 256 * 2;
    float4* a_s1 = (float4*)w; w += (size_t)N_NODES * 16;
    float4* a_d1 = (float4*)w; w += (size_t)N_NODES * 16;
    unsigned short* h2b = (unsigned short*)w; w += (size_t)N_NODES * 64 * 2;
    float* out2  = (float*)w; w += (size_t)N_NODES * 64 * 4;
    float* a_s2  = (float*)w; w += (size_t)N_NODES * 4;
    float* a_d2  = (float*)w; w += (size_t)N_NODES * 4;
    int* counts    = (int*)w; w += (size_t)N_NODES * 4;
    int* row_start = (int*)w; w += (size_t)(N_NODES + 64) * 4;
    int* cursor    = (int*)w; w += (size_t)N_NODES * 4;
    int* csr_src   = (int*)w; w += (size_t)N_EDGES * 4;
    int* blk_sum   = (int*)w; w += 128 * 4;
    int* blk_base  = (int*)w; w += 128 * 4;

    // CSR build (multi-block scan)
    hipMemsetAsync(counts, 0, (size_t)N_NODES * 4, stream);
    k_count<<<(N_EDGES + 255) / 256, 256, 0, stream>>>(dst, counts);
    k_scan1<<<SCAN_NB, SCAN_BS, 0, stream>>>(counts, cursor, blk_sum);
    k_scan2<<<1, 128, 0, stream>>>(blk_sum, blk_base, row_start);
    k_scan3<<<SCAN_NB, SCAN_BS, 0, stream>>>(cursor, blk_base, row_start, cursor);
    k_fill<<<(N_EDGES + 255) / 256, 256, 0, stream>>>(src, dst, cursor, csr_src);

    // Layer 1
    k_gemm1<<<(N_NODES + 3) / 4, 256, 0, stream>>>(x, W1, as1, ad1, a_s1, a_d1);
    k_agg1<<<(N_NODES + 3) / 4, 256, 0, stream>>>(x, W1, a_s1, a_d1, row_start, csr_src, b1, out1rm);
    // Layer 2 (MFMA)
    k_gemm2<<<(N_NODES + 63) / 64, 256, 0, stream>>>(out1rm, W2, as2, ad2, h2b, a_s2, a_d2);
    k_agg2<<<(N_NODES + 3) / 4, 256, 0, stream>>>(h2b, a_s2, a_d2, row_start, csr_src, b2, out2);

    // Pool + linear
    k_pool<<<N_GRAPHS, 256, 0, stream>>>(out2, bat, linW, linb, out);
}

// Round 9
// 264.291 us; speedup vs baseline: 2.8775x; 1.0916x over previous
//
#include <hip/hip_runtime.h>
#include <math.h>

#define N_NODES 50000
#define N_EDGES 800000
#define N_GRAPHS 64
#define NEG_SLOPE 0.2f
#define SCAN_BS 512
#define SCAN_NB ((N_NODES + SCAN_BS - 1) / SCAN_BS)   // 98

typedef __attribute__((ext_vector_type(8))) short short8;
typedef __attribute__((ext_vector_type(4))) float f32x4;

__device__ __forceinline__ float lrelu(float x) { return x > 0.f ? x : NEG_SLOPE * x; }

__device__ __forceinline__ unsigned short f2bf(float f) {
    union { float f; unsigned int u; } v; v.f = f;
    unsigned int r = (v.u + 0x7fffu + ((v.u >> 16) & 1u)) >> 16;  // RNE
    return (unsigned short)r;
}
__device__ __forceinline__ float bf2f(unsigned short b) {
    union { unsigned int u; float f; } v; v.u = ((unsigned int)b) << 16;
    return v.f;
}

__device__ __forceinline__ int lower_bound_i(const int* __restrict__ a, int n, int v) {
    int lo = 0, hi = n;
    while (lo < hi) { int m = (lo + hi) >> 1; if (a[m] < v) lo = m + 1; else hi = m; }
    return lo;
}

// ---------------- CSR build ----------------
__global__ void k_count(const int* __restrict__ dst, int* __restrict__ cnt) {
    int e = blockIdx.x * blockDim.x + threadIdx.x;
    if (e < N_EDGES) atomicAdd(&cnt[dst[e]], 1);
}

__global__ __launch_bounds__(SCAN_BS) void k_scan1(const int* __restrict__ cnt,
                                                   int* __restrict__ local_pref,
                                                   int* __restrict__ blk_sum) {
    const int t = threadIdx.x;
    const int gid = blockIdx.x * SCAN_BS + t;
    const int lane = t & 63, w = t >> 6;
    int v = (gid < N_NODES) ? cnt[gid] : 0;
    int x = v;
#pragma unroll
    for (int off = 1; off < 64; off <<= 1) {
        int y = __shfl_up(x, off, 64);
        if (lane >= off) x += y;
    }
    __shared__ int wsum[SCAN_BS / 64];
    __shared__ int wpre[SCAN_BS / 64];
    if (lane == 63) wsum[w] = x;
    __syncthreads();
    if (t == 0) {
        int run = 0;
#pragma unroll
        for (int i = 0; i < SCAN_BS / 64; ++i) { wpre[i] = run; run += wsum[i]; }
    }
    __syncthreads();
    int excl = x - v + wpre[w];
    if (gid < N_NODES) local_pref[gid] = excl;
    if (t == SCAN_BS - 1) blk_sum[blockIdx.x] = excl + v;
}

__global__ __launch_bounds__(128) void k_scan2(const int* __restrict__ blk_sum,
                                               int* __restrict__ blk_base,
                                               int* __restrict__ row_start) {
    const int t = threadIdx.x;
    const int lane = t & 63;
    int v = (t < SCAN_NB) ? blk_sum[t] : 0;
    int x = v;
#pragma unroll
    for (int off = 1; off < 64; off <<= 1) {
        int y = __shfl_up(x, off, 64);
        if (lane >= off) x += y;
    }
    __shared__ int wsum0;
    if (t == 63) wsum0 = x;
    __syncthreads();
    int excl = x - v + ((t >= 64) ? wsum0 : 0);
    if (t < SCAN_NB) blk_base[t] = excl;
    if (t == 127) row_start[N_NODES] = excl + v;  // grand total
}

__global__ __launch_bounds__(SCAN_BS) void k_scan3(const int* __restrict__ local_pref,
                                                   const int* __restrict__ blk_base,
                                                   int* __restrict__ row_start,
                                                   int* __restrict__ cursor) {
    const int gid = blockIdx.x * SCAN_BS + threadIdx.x;
    if (gid < N_NODES) {
        int r = local_pref[gid] + blk_base[blockIdx.x];
        row_start[gid] = r;
        cursor[gid] = r;
    }
}

__global__ void k_fill(const int* __restrict__ src, const int* __restrict__ dst,
                       int* __restrict__ cursor, int* __restrict__ csr_src) {
    int e = blockIdx.x * blockDim.x + threadIdx.x;
    if (e < N_EDGES) {
        int d = dst[e];
        int p = atomicAdd(&cursor[d], 1);
        csr_src[p] = src[e];
    }
}

// ---------------- Layer 1 logits: a_s/a_d per node (h1 NOT materialized) -----
__global__ __launch_bounds__(256) void k_gemm1(const float* __restrict__ x,
                                               const float* __restrict__ W1,
                                               const float* __restrict__ att_s,
                                               const float* __restrict__ att_d,
                                               float4* __restrict__ a_s,
                                               float4* __restrict__ a_d) {
    __shared__ float Ws[5 * 256];
    const int t = threadIdx.x;
    for (int i = t; i < 5 * 256; i += 256) Ws[i] = W1[i];
    __syncthreads();
    const int wave = t >> 6, lane = t & 63;
    const int n = blockIdx.x * 4 + wave;
    if (n >= N_NODES) return;
    float x0 = x[n * 5 + 0], x1 = x[n * 5 + 1], x2 = x[n * 5 + 2],
          x3 = x[n * 5 + 3], x4 = x[n * 5 + 4];
    float vs[4], vd[4];
#pragma unroll
    for (int hd = 0; hd < 4; ++hd) {
        const int c = hd * 64 + lane;
        float h = x0 * Ws[c] + x1 * Ws[256 + c] + x2 * Ws[512 + c] +
                  x3 * Ws[768 + c] + x4 * Ws[1024 + c];
        vs[hd] = h * att_s[c];
        vd[hd] = h * att_d[c];
    }
#pragma unroll
    for (int off = 32; off; off >>= 1) {
#pragma unroll
        for (int hd = 0; hd < 4; ++hd) {
            vs[hd] += __shfl_xor(vs[hd], off, 64);
            vd[hd] += __shfl_xor(vd[hd], off, 64);
        }
    }
    if (lane == 0) {
        a_s[n] = make_float4(vs[0], vs[1], vs[2], vs[3]);
        a_d[n] = make_float4(vd[0], vd[1], vd[2], vd[3]);
    }
}

// ---------------- Layer 1 aggregation: SUM-SWAPPED ----------------
// out1[d][c] = relu( (1/den_H) * sum_i W1[i][c] * Xw[H][i] + b1[c] ),
// where Xw[H][i] = sum_{e in N(d)} w_eH * x[src_e][i]  (24-dim lane-local accum).
// 16 lanes per node (50000 = 3125*16 exact); butterfly reduce; LDS handoff;
// 64-lane epilogue applies W1 once per node.
__global__ __launch_bounds__(256) void k_agg1(const float* __restrict__ x,
                                              const float* __restrict__ W1,
                                              const float4* __restrict__ asv,
                                              const float4* __restrict__ adv,
                                              const int* __restrict__ row_start,
                                              const int* __restrict__ csr_src,
                                              const float* __restrict__ b1,
                                              unsigned short* __restrict__ out1rm) {
    __shared__ float hand[4][4][24];   // [wave][grp][4 den + 20 Xw]
    const int t = threadIdx.x;
    const int wave = t >> 6, lane = t & 63;
    const int grp = lane >> 4, l16 = lane & 15;
    const int d = blockIdx.x * 16 + wave * 4 + grp;   // exact cover

    // epilogue constants (channel = h*64 + lane)
    float w1r[4][5], bias[4];
#pragma unroll
    for (int h = 0; h < 4; ++h) {
#pragma unroll
        for (int i = 0; i < 5; ++i) w1r[h][i] = W1[i * 256 + h * 64 + lane];
        bias[h] = b1[h * 64 + lane];
    }

    const int beg = row_start[d], end = row_start[d + 1];
    const float4 ad = adv[d];

    float den[4] = {0.f, 0.f, 0.f, 0.f};
    float xw[4][5];
#pragma unroll
    for (int h = 0; h < 4; ++h)
#pragma unroll
        for (int i = 0; i < 5; ++i) xw[h][i] = 0.f;

    // edge phase: lane = edge, all accumulation lane-local
    for (int cb = beg; cb < end; cb += 16) {
        const int j = cb + l16;
        if (j < end) {
            const int s = csr_src[j];
            const float4 a = asv[s];
            float w[4];
            w[0] = __expf(lrelu(a.x + ad.x));
            w[1] = __expf(lrelu(a.y + ad.y));
            w[2] = __expf(lrelu(a.z + ad.z));
            w[3] = __expf(lrelu(a.w + ad.w));
            const float* xp = x + (size_t)s * 5;
            float xv[5];
#pragma unroll
            for (int i = 0; i < 5; ++i) xv[i] = xp[i];
#pragma unroll
            for (int h = 0; h < 4; ++h) {
                den[h] += w[h];
#pragma unroll
                for (int i = 0; i < 5; ++i) xw[h][i] += w[h] * xv[i];
            }
        }
    }

    // butterfly reduce within 16-lane group (all lanes end with totals)
#pragma unroll
    for (int off = 1; off < 16; off <<= 1) {
#pragma unroll
        for (int h = 0; h < 4; ++h) {
            den[h] += __shfl_xor(den[h], off, 64);
#pragma unroll
            for (int i = 0; i < 5; ++i) xw[h][i] += __shfl_xor(xw[h][i], off, 64);
        }
    }

    // self loop (uniform per group)
    {
        const float4 as = asv[d];
        float w[4];
        w[0] = __expf(lrelu(as.x + ad.x));
        w[1] = __expf(lrelu(as.y + ad.y));
        w[2] = __expf(lrelu(as.z + ad.z));
        w[3] = __expf(lrelu(as.w + ad.w));
        const float* xp = x + (size_t)d * 5;
        float xv[5];
#pragma unroll
        for (int i = 0; i < 5; ++i) xv[i] = xp[i];
#pragma unroll
        for (int h = 0; h < 4; ++h) {
            den[h] += w[h];
#pragma unroll
            for (int i = 0; i < 5; ++i) xw[h][i] += w[h] * xv[i];
        }
    }

    if (l16 == 0) {
#pragma unroll
        for (int h = 0; h < 4; ++h) hand[wave][grp][h] = den[h];
#pragma unroll
        for (int h = 0; h < 4; ++h)
#pragma unroll
            for (int i = 0; i < 5; ++i) hand[wave][grp][4 + h * 5 + i] = xw[h][i];
    }
    __syncthreads();

    // 64-lane epilogue over this wave's 4 nodes
#pragma unroll
    for (int n = 0; n < 4; ++n) {
        const int dn = blockIdx.x * 16 + wave * 4 + n;
        unsigned short* op = out1rm + (size_t)dn * 256;
#pragma unroll
        for (int h = 0; h < 4; ++h) {
            const float dh = hand[wave][n][h] + 1e-16f;
            float hh = hand[wave][n][4 + h * 5 + 0] * w1r[h][0]
                     + hand[wave][n][4 + h * 5 + 1] * w1r[h][1]
                     + hand[wave][n][4 + h * 5 + 2] * w1r[h][2]
                     + hand[wave][n][4 + h * 5 + 3] * w1r[h][3]
                     + hand[wave][n][4 + h * 5 + 4] * w1r[h][4];
            op[h * 64 + lane] = f2bf(fmaxf(hh / dh + bias[h], 0.f));
        }
    }
}

// ---------------- Layer 2: MFMA GEMM (50000x256 @ 256x64) + attention logits ----
__global__ __launch_bounds__(256) void k_gemm2(const unsigned short* __restrict__ in,
                                               const float* __restrict__ W2,
                                               const float* __restrict__ att_s2,
                                               const float* __restrict__ att_d2,
                                               unsigned short* __restrict__ h2b,
                                               float* __restrict__ a_s2,
                                               float* __restrict__ a_d2) {
    __shared__ unsigned short lW[16384];  // 32 KB: [s][g][t][c16][j]
    const int t = threadIdx.x;
    for (int idx = t; idx < 16384; idx += 256) {
        int j = idx & 7, c16 = (idx >> 3) & 15, tt = (idx >> 7) & 3,
            g = (idx >> 9) & 3, s = idx >> 11;
        int k = 32 * s + 8 * g + j, c = 16 * tt + c16;
        lW[idx] = f2bf(W2[k * 64 + c]);
    }
    __syncthreads();
    const int wave = t >> 6, lane = t & 63;
    const int g = lane >> 4, c16 = lane & 15;
    const int nb = blockIdx.x * 64 + wave * 16;
    if (nb >= N_NODES) return;

    f32x4 acc[4];
#pragma unroll
    for (int i = 0; i < 4; ++i) acc[i] = (f32x4){0.f, 0.f, 0.f, 0.f};

    const unsigned short* arow = in + (size_t)(nb + c16) * 256;  // A row = lane&15
#pragma unroll
    for (int s = 0; s < 8; ++s) {
        short8 a = *reinterpret_cast<const short8*>(arow + 32 * s + 8 * g);
#pragma unroll
        for (int tt = 0; tt < 4; ++tt) {
            short8 b = *reinterpret_cast<const short8*>(
                lW + ((((s * 4 + g) * 4 + tt) * 16 + c16) << 3));
            acc[tt] = __builtin_amdgcn_mfma_f32_16x16x32_bf16(a, b, acc[tt], 0, 0, 0);
        }
    }

    float attS[4], attD[4];
#pragma unroll
    for (int tt = 0; tt < 4; ++tt) {
        attS[tt] = att_s2[16 * tt + c16];
        attD[tt] = att_d2[16 * tt + c16];
    }
#pragma unroll
    for (int r = 0; r < 4; ++r) {
        const int node = nb + g * 4 + r;
        const bool ok = node < N_NODES;
        float vs = 0.f, vd = 0.f;
#pragma unroll
        for (int tt = 0; tt < 4; ++tt) {
            float v = acc[tt][r];
            if (ok) h2b[(size_t)node * 64 + 16 * tt + c16] = f2bf(v);
            vs += v * attS[tt];
            vd += v * attD[tt];
        }
#pragma unroll
        for (int off = 1; off < 16; off <<= 1) {
            vs += __shfl_xor(vs, off, 64);
            vd += __shfl_xor(vd, off, 64);
        }
        if (ok && c16 == 0) { a_s2[node] = vs; a_d2[node] = vd; }
    }
}

// ---------------- Layer 2 aggregation: wave per dst node (no-max softmax) -----
__global__ __launch_bounds__(256) void k_agg2(const unsigned short* __restrict__ h2b,
                                              const float* __restrict__ as_,
                                              const float* __restrict__ ad_,
                                              const int* __restrict__ row_start,
                                              const int* __restrict__ csr_src,
                                              const float* __restrict__ b2,
                                              float* __restrict__ out2) {
    const int wave = threadIdx.x >> 6, lane = threadIdx.x & 63;
    const int d = blockIdx.x * 4 + wave;
    if (d >= N_NODES) return;
    const int beg = row_start[d], end = row_start[d + 1];
    const float adl = ad_[d];

    float den, acc;
    {
        float w = __expf(lrelu(as_[d] + adl));
        den = (lane == 0) ? w : 0.f;
        acc = w * bf2f(h2b[(size_t)d * 64 + lane]);
    }
    for (int c = beg; c < end; c += 64) {
        int rem = end - c; if (rem > 64) rem = 64;
        int sreg = 0;
        float wr = 0.f;
        if (lane < rem) {
            sreg = csr_src[c + lane];
            wr = __expf(lrelu(as_[sreg] + adl));
            den += wr;
        }
        int e = 0;
        for (; e + 8 <= rem; e += 8) {
            int sq[8];
#pragma unroll
            for (int q = 0; q < 8; ++q) sq[q] = __shfl(sreg, e + q, 64);
            unsigned short vq[8];
#pragma unroll
            for (int q = 0; q < 8; ++q) vq[q] = h2b[(size_t)sq[q] * 64 + lane];
#pragma unroll
            for (int q = 0; q < 8; ++q) {
                acc += __shfl(wr, e + q, 64) * bf2f(vq[q]);
            }
        }
        for (; e < rem; ++e) {
            int s = __shfl(sreg, e, 64);
            acc += __shfl(wr, e, 64) * bf2f(h2b[(size_t)s * 64 + lane]);
        }
    }
#pragma unroll
    for (int off = 32; off; off >>= 1) den += __shfl_xor(den, off, 64);
    out2[(size_t)d * 64 + lane] = fmaxf(acc / (den + 1e-16f) + b2[lane], 0.f);
}

// ---------------- Global mean pool + linear ----------------
__global__ __launch_bounds__(256) void k_pool(const float* __restrict__ out2,
                                              const int* __restrict__ batch,
                                              const float* __restrict__ linW,
                                              const float* __restrict__ linb,
                                              float* __restrict__ out) {
    const int g = blockIdx.x;
    const int t = threadIdx.x, wave = t >> 6, lane = t & 63;
    __shared__ int s_beg, s_end;
    __shared__ float red[4][64];
    if (t == 0) {
        s_beg = lower_bound_i(batch, N_NODES, g);
        s_end = lower_bound_i(batch, N_NODES, g + 1);
    }
    __syncthreads();
    const int beg = s_beg, end = s_end;
    float sum = 0.f;
    for (int n = beg + wave; n < end; n += 4) sum += out2[(size_t)n * 64 + lane];
    red[wave][lane] = sum;
    __syncthreads();
    if (wave == 0) {
        float s = red[0][lane] + red[1][lane] + red[2][lane] + red[3][lane];
        float cnt = (float)(end - beg);
        red[0][lane] = s / fmaxf(cnt, 1.0f);
    }
    __syncthreads();
    if (t < 2) {
        float acc = linb[t];
        for (int c = 0; c < 64; ++c) acc += red[0][c] * linW[c * 2 + t];
        out[g * 2 + t] = acc;
    }
}

extern "C" void kernel_launch(void* const* d_in, const int* in_sizes, int n_in,
                              void* d_out, int out_size, void* d_ws, size_t ws_size,
                              hipStream_t stream) {
    const float* x    = (const float*)d_in[0];
    const int*   ei   = (const int*)d_in[1];
    const int*   bat  = (const int*)d_in[2];
    const float* W1   = (const float*)d_in[3];
    const float* as1  = (const float*)d_in[4];
    const float* ad1  = (const float*)d_in[5];
    const float* b1   = (const float*)d_in[6];
    const float* W2   = (const float*)d_in[7];
    const float* as2  = (const float*)d_in[8];
    const float* ad2  = (const float*)d_in[9];
    const float* b2   = (const float*)d_in[10];
    const float* linW = (const float*)d_in[11];
    const float* linb = (const float*)d_in[12];
    float* out = (float*)d_out;

    const int* src = ei;
    const int* dst = ei + N_EDGES;

    char* w = (char*)d_ws;
    unsigned short* out1rm = (unsigned short*)w; w += (size_t)N_NODES * 256 * 2;
    float4* a_s1 = (float4*)w; w += (size_t)N_NODES * 16;
    float4* a_d1 = (float4*)w; w += (size_t)N_NODES * 16;
    unsigned short* h2b = (unsigned short*)w; w += (size_t)N_NODES * 64 * 2;
    float* out2  = (float*)w; w += (size_t)N_NODES * 64 * 4;
    float* a_s2  = (float*)w; w += (size_t)N_NODES * 4;
    float* a_d2  = (float*)w; w += (size_t)N_NODES * 4;
    int* counts    = (int*)w; w += (size_t)N_NODES * 4;
    int* row_start = (int*)w; w += (size_t)(N_NODES + 64) * 4;
    int* cursor    = (int*)w; w += (size_t)N_NODES * 4;
    int* csr_src   = (int*)w; w += (size_t)N_EDGES * 4;
    int* blk_sum   = (int*)w; w += 128 * 4;
    int* blk_base  = (int*)w; w += 128 * 4;

    // CSR build (multi-block scan)
    hipMemsetAsync(counts, 0, (size_t)N_NODES * 4, stream);
    k_count<<<(N_EDGES + 255) / 256, 256, 0, stream>>>(dst, counts);
    k_scan1<<<SCAN_NB, SCAN_BS, 0, stream>>>(counts, cursor, blk_sum);
    k_scan2<<<1, 128, 0, stream>>>(blk_sum, blk_base, row_start);
    k_scan3<<<SCAN_NB, SCAN_BS, 0, stream>>>(cursor, blk_base, row_start, cursor);
    k_fill<<<(N_EDGES + 255) / 256, 256, 0, stream>>>(src, dst, cursor, csr_src);

    // Layer 1
    k_gemm1<<<(N_NODES + 3) / 4, 256, 0, stream>>>(x, W1, as1, ad1, a_s1, a_d1);
    k_agg1<<<N_NODES / 16, 256, 0, stream>>>(x, W1, a_s1, a_d1, row_start, csr_src, b1, out1rm);
    // Layer 2 (MFMA)
    k_gemm2<<<(N_NODES + 63) / 64, 256, 0, stream>>>(out1rm, W2, as2, ad2, h2b, a_s2, a_d2);
    k_agg2<<<(N_NODES + 3) / 4, 256, 0, stream>>>(h2b, a_s2, a_d2, row_start, csr_src, b2, out2);

    // Pool + linear
    k_pool<<<N_GRAPHS, 256, 0, stream>>>(out2, bat, linW, linb, out);
}